// Round 7
// baseline (353.234 us; speedup 1.0000x reference)
//
#include <hip/hip_runtime.h>
#include <math.h>

#define BATCH 4
#define NSUP 25
#define NQ   75
#define CH   640
#define HW   100
#define NWAY 5
#define KSHOT 5
#define NSYS (BATCH*NQ)   // 300
#define MS   (NWAY*HW)    // 500
#define MQ   HW           // 100
#define MTOT (NQ*HW)      // 7500 rows per batch

typedef __attribute__((ext_vector_type(8))) short bf16x8;
typedef __attribute__((ext_vector_type(4))) float f32x4;

__device__ __forceinline__ ushort f2bf(float f) {
    unsigned u = __float_as_uint(f);
    u += 0x7fff + ((u >> 16) & 1);          // RNE
    return (ushort)(u >> 16);
}
__device__ __forceinline__ float bf2f(ushort h) {
    return __uint_as_float(((unsigned)h) << 16);
}

#define GLD_LDS16(gp, lp) __builtin_amdgcn_global_load_lds( \
    (const __attribute__((address_space(1))) unsigned*)(const void*)(gp), \
    (__attribute__((address_space(3))) unsigned*)(void*)(lp), 16, 0, 0)

// ---------------- K1: transpose + raw bf16 hi/lo split + norm partials (query) ----------------
__global__ __launch_bounds__(256) void k_prep(const float* __restrict__ in,
        ushort* __restrict__ hi, ushort* __restrict__ lo,
        float* __restrict__ normpart, int planesHW) {
    __shared__ float tile[64][65];
    int p  = blockIdx.z;
    int c0 = blockIdx.x * 64;
    int m0 = blockIdx.y * 64;
    int t  = threadIdx.x;
    const float* ib = in + (size_t)p*CH*HW;
#pragma unroll
    for (int i = 0; i < 16; ++i) {
        int l = i*256 + t;
        int cl = l >> 6, ml = l & 63;
        int m = m0 + ml;
        tile[cl][ml] = (m < HW) ? ib[(size_t)(c0+cl)*HW + m] : 0.f;
    }
    __syncthreads();
    if (t < 64 && (m0 + t) < HW) {
        float s = 0.f;
#pragma unroll
        for (int cl = 0; cl < 64; ++cl) { float v = tile[cl][t]; s += v*v; }
        normpart[(size_t)blockIdx.x*planesHW + p*HW + m0 + t] = s;
    }
#pragma unroll
    for (int i = 0; i < 16; ++i) {
        int l = i*256 + t;
        int ml = l >> 6, cl = l & 63;
        int m = m0 + ml;
        if (m < HW) {
            size_t r = (size_t)p*HW + m;
            float v = tile[cl][ml];
            ushort h = f2bf(v);
            float fl = v - bf2f(h);
            hi[r*CH + c0 + cl] = h;
            lo[r*CH + c0 + cl] = f2bf(fl);
        }
    }
}

// ---------------- K1b: support variant — fused 5-shot class mean ----------------
__global__ __launch_bounds__(256) void k_prep_sup(const float* __restrict__ sup,
        ushort* __restrict__ hi, ushort* __restrict__ lo,
        float* __restrict__ normpart) {
    __shared__ float tile[64][65];
    int p  = blockIdx.z;              // b*NWAY + n
    int c0 = blockIdx.x * 64;
    int m0 = blockIdx.y * 64;
    int t  = threadIdx.x;
    int b = p / NWAY, n = p % NWAY;
    const float* ib = sup + ((size_t)(b*NSUP + n*KSHOT))*CH*HW;
#pragma unroll
    for (int i = 0; i < 16; ++i) {
        int l = i*256 + t;
        int cl = l >> 6, ml = l & 63;
        int m = m0 + ml;
        float a = 0.f;
        if (m < HW) {
#pragma unroll
            for (int k = 0; k < KSHOT; ++k)
                a += ib[((size_t)k*CH + c0 + cl)*HW + m];
        }
        tile[cl][ml] = a * 0.2f;
    }
    __syncthreads();
    if (t < 64 && (m0 + t) < HW) {
        float s = 0.f;
#pragma unroll
        for (int cl = 0; cl < 64; ++cl) { float v = tile[cl][t]; s += v*v; }
        normpart[(size_t)blockIdx.x*(BATCH*NWAY*HW) + p*HW + m0 + t] = s;
    }
#pragma unroll
    for (int i = 0; i < 16; ++i) {
        int l = i*256 + t;
        int ml = l >> 6, cl = l & 63;
        int m = m0 + ml;
        if (m < HW) {
            size_t r = (size_t)p*HW + m;
            float v = tile[cl][ml];
            ushort h = f2bf(v);
            float fl = v - bf2f(h);
            hi[r*CH + c0 + cl] = h;
            lo[r*CH + c0 + cl] = f2bf(fl);
        }
    }
}

// ---------------- K2: finish inverse norms (query + support merged) ----------------
__global__ void k_finishinv(const float* __restrict__ pq, const float* __restrict__ ps,
                            float* __restrict__ invq, float* __restrict__ invs) {
    int idx = blockIdx.x * 256 + threadIdx.x;
    if (idx < NSYS*HW) {
        float s = 0.f;
#pragma unroll
        for (int u = 0; u < 10; ++u) s += pq[(size_t)u*(NSYS*HW) + idx];
        invq[idx] = 1.0f / (1e-16f + sqrtf(s));
    } else {
        int j = idx - NSYS*HW;
        if (j < BATCH*NWAY*HW) {
            float s = 0.f;
#pragma unroll
            for (int u = 0; u < 10; ++u) s += ps[(size_t)u*(BATCH*NWAY*HW) + j];
            invs[j] = 1.0f / (1e-16f + sqrtf(s));
        }
    }
}

// ---------------- K3: split-bf16 MFMA GEMM, 128x128 tile, dbuf + counted vmcnt ----------------
#define BM 128
#define BN 128
#define BK 32
#define NKT (CH/BK)           // 20
#define NCT 4
#define NRT 59
#define NWG (NCT*NRT*BATCH)   // 944, divisible by 8
#define BUFB 32768
// Per buffer: A rows 0..127 at r*128, B rows(cols) 0..127 at 16384 + r*128.
// Row = 8 slots of 16B; logical slot s (s<4: hi k-group s, s>=4: lo k-group s-4)
// stored at slot sp = s ^ (r&7). 128B rows + 8-slot XOR => 0 conflicts (measured R6).
__global__ __launch_bounds__(256) void k_gemm(
        const ushort* __restrict__ Ah, const ushort* __restrict__ Al,
        const ushort* __restrict__ Bh, const ushort* __restrict__ Bl,
        const float* __restrict__ invq, const float* __restrict__ invs,
        float* __restrict__ S) {
    __shared__ __align__(1024) char lds[65536];
    int hwid = blockIdx.x;
    int l = (hwid & 7) * (NWG/8) + (hwid >> 3);   // chunked XCD swizzle
    int ct = l & 3;
    int rest = l >> 2;            // 0..235
    int rt = rest % NRT;
    int b  = rest / NRT;
    int t  = threadIdx.x;
    int lane = t & 63, w = t >> 6;
    int row0 = rt * BM, col0 = ct * BN;

    // per-thread staging sources: chunk i -> LDS byte i*4096 + t*16 (A), 16384+... (B)
    const ushort* srcA[4];
    const ushort* srcB[4];
#pragma unroll
    for (int i = 0; i < 4; ++i) {
        int X = i*4096 + t*16;
        int row = X >> 7;
        int sp  = (X >> 4) & 7;
        int s   = sp ^ (row & 7);
        int gr = row0 + row; if (gr > MTOT-1) gr = MTOT-1;
        srcA[i] = ((s & 4) ? Al : Ah) + ((size_t)b*MTOT + gr)*CH + (s & 3)*8;
        int gc = col0 + row; if (gc > MS-1) gc = MS-1;
        srcB[i] = ((s & 4) ? Bl : Bh) + ((size_t)b*MS + gc)*CH + (s & 3)*8;
    }
    int dA = w << 10;   // wave-uniform dest base within each 4KB chunk region

    f32x4 acc[4][4];
#pragma unroll
    for (int mi = 0; mi < 4; ++mi)
#pragma unroll
        for (int ni = 0; ni < 4; ++ni) acc[mi][ni] = (f32x4){0.f,0.f,0.f,0.f};

    int wr = w >> 1, wc = w & 1;
    int q = lane & 15, kg = lane >> 4;

#define STAGE(bufb, kt_) do { \
        int ko = (kt_) * BK; \
        char* bb = lds + (bufb)*BUFB; \
        GLD_LDS16(srcA[0] + ko, bb + 0     + dA); \
        GLD_LDS16(srcA[1] + ko, bb + 4096  + dA); \
        GLD_LDS16(srcA[2] + ko, bb + 8192  + dA); \
        GLD_LDS16(srcA[3] + ko, bb + 12288 + dA); \
        GLD_LDS16(srcB[0] + ko, bb + 16384 + dA); \
        GLD_LDS16(srcB[1] + ko, bb + 20480 + dA); \
        GLD_LDS16(srcB[2] + ko, bb + 24576 + dA); \
        GLD_LDS16(srcB[3] + ko, bb + 28672 + dA); \
    } while (0)

    STAGE(0, 0);
    for (int kt = 0; kt < NKT; ++kt) {
        int cur = kt & 1;
        if (kt + 1 < NKT) {
            STAGE(cur ^ 1, kt + 1);
            asm volatile("s_waitcnt vmcnt(8)" ::: "memory");
        } else {
            asm volatile("s_waitcnt vmcnt(0)" ::: "memory");
        }
        __builtin_amdgcn_sched_barrier(0);
        __builtin_amdgcn_s_barrier();
        __builtin_amdgcn_sched_barrier(0);

        const char* base = lds + cur*BUFB;
        bf16x8 bh[4], bl[4];
#pragma unroll
        for (int ni = 0; ni < 4; ++ni) {
            int colr = wc*64 + ni*16 + q;
            int rb = 16384 + colr*128;
            bh[ni] = *(const bf16x8*)(base + rb + (((kg    ) ^ (colr & 7)) << 4));
            bl[ni] = *(const bf16x8*)(base + rb + (((kg | 4) ^ (colr & 7)) << 4));
        }
#pragma unroll
        for (int mi = 0; mi < 4; ++mi) {
            int rowr = wr*64 + mi*16 + q;
            int rb = rowr*128;
            bf16x8 ah = *(const bf16x8*)(base + rb + (((kg    ) ^ (rowr & 7)) << 4));
            bf16x8 al = *(const bf16x8*)(base + rb + (((kg | 4) ^ (rowr & 7)) << 4));
#pragma unroll
            for (int ni = 0; ni < 4; ++ni) {
                acc[mi][ni] = __builtin_amdgcn_mfma_f32_16x16x32_bf16(ah, bh[ni], acc[mi][ni], 0, 0, 0);
                acc[mi][ni] = __builtin_amdgcn_mfma_f32_16x16x32_bf16(ah, bl[ni], acc[mi][ni], 0, 0, 0);
                acc[mi][ni] = __builtin_amdgcn_mfma_f32_16x16x32_bf16(al, bh[ni], acc[mi][ni], 0, 0, 0);
            }
        }
        __builtin_amdgcn_sched_barrier(0);
        __builtin_amdgcn_s_barrier();
        __builtin_amdgcn_sched_barrier(0);
    }
#undef STAGE

    int colb = col0 + wc*64 + q;
    int rowb = row0 + wr*64 + (kg << 2);
#pragma unroll
    for (int mi = 0; mi < 4; ++mi) {
#pragma unroll
        for (int ni = 0; ni < 4; ++ni) {
            int c = colb + ni*16;
            if (c >= MS) continue;
            float si = invs[b*MS + c];
#pragma unroll
            for (int j = 0; j < 4; ++j) {
                int r = rowb + mi*16 + j;
                if (r < MTOT)
                    S[((size_t)b*MTOT + r)*MS + c] = acc[mi][ni][j] * invq[b*MTOT + r] * si;
            }
        }
    }
}

// ---------------- K4: fused stats + formB + Jacobi solve + normalize, one block/sys ----------------
#define KC 50
#define PADP 102
__global__ __launch_bounds__(512) void k_post(const float* __restrict__ S,
                                              float* __restrict__ out) {
    __shared__ __align__(16) char sm[41984];        // aliased: stats wcm/wcs | PT/QT | Bsh
    __shared__ float m20s[MQ], r20s[MQ];
    __shared__ float m10s[MS], r10s[MS];
    __shared__ float xs[MQ], rh[MQ];
    __shared__ float partial[2];
    int sys = blockIdx.x;
    int t = threadIdx.x;
    int w = t >> 6, l = t & 63;
    const float* Sb = S + (size_t)sys*MQ*MS;

    // ---- phase 1: fused row(g20) + col(g10) softmax stats, single S pass ----
    {
        float (*wcm)[512] = (float(*)[512])sm;          // [8][512]
        float (*wcs)[512] = (float(*)[512])(sm + 16384);
        float colm[8], cols[8];
#pragma unroll
        for (int u = 0; u < 8; ++u) { colm[u] = -1e30f; cols[u] = 0.f; }
        int nu = (l < MS - 448) ? 8 : 7;   // l<52 -> 8 cols
        for (int row = w; row < MQ; row += 8) {
            const float* rp = Sb + (size_t)row*MS;
            float v[8];
            float rm = -1e30f;
#pragma unroll
            for (int u = 0; u < 8; ++u) {
                v[u] = (u < nu) ? rp[l + 64*u] : -1e30f;
                rm = fmaxf(rm, v[u]);
            }
            for (int off = 32; off; off >>= 1) rm = fmaxf(rm, __shfl_xor(rm, off));
            float rs = 0.f;
#pragma unroll
            for (int u = 0; u < 8; ++u) if (u < nu) rs += __expf(20.f*(v[u]-rm));
            for (int off = 32; off; off >>= 1) rs += __shfl_xor(rs, off);
            if (l == 0) { m20s[row] = rm; r20s[row] = 1.0f/rs; }
#pragma unroll
            for (int u = 0; u < 8; ++u) if (u < nu) {
                float vv = v[u];
                if (vv <= colm[u]) {
                    cols[u] += __expf(10.f*(vv - colm[u]));
                } else {
                    cols[u] = cols[u]*__expf(10.f*(colm[u]-vv)) + 1.0f;
                    colm[u] = vv;
                }
            }
        }
#pragma unroll
        for (int u = 0; u < 8; ++u) { wcm[w][l+64*u] = colm[u]; wcs[w][l+64*u] = cols[u]; }
        __syncthreads();
        if (t < MS) {
            float m = -1e30f;
#pragma unroll
            for (int w2 = 0; w2 < 8; ++w2) m = fmaxf(m, wcm[w2][t]);
            float s = 0.f;
#pragma unroll
            for (int w2 = 0; w2 < 8; ++w2) s += wcs[w2][t]*__expf(10.f*(wcm[w2][t]-m));
            m10s[t] = m;
            r10s[t] = 1.0f/s;
        }
        __syncthreads();
    }

    // ---- phase 2: B[i][j] = sum_c P[i][c]*Q[j][c] in registers, 10 chunks of 50 ----
    float (*PT)[PADP] = (float(*)[PADP])sm;             // [KC][102]
    float (*QT)[PADP] = (float(*)[PADP])(sm + 20480);
    int tx = t % 25, ty = t / 25;       // ty<20 compute: i0=tx*4 (4 rows), j0=ty*5 (5 cols)
    int i0 = tx*4, j0 = ty*5;
    float acc[4][5] = {};
    float rs = 0.f;
    for (int col0 = 0; col0 < MS; col0 += KC) {
        __syncthreads();
        for (int ll = t; ll < MQ*KC; ll += 512) {
            int r = ll / KC, c = ll % KC;
            float v = Sb[(size_t)r*MS + col0 + c];
            PT[c][r] = __expf(10.f*(v - m10s[col0+c])) * r10s[col0+c];
            QT[c][r] = __expf(20.f*(v - m20s[r])) * r20s[r];
        }
        __syncthreads();
        if (t < MQ) {
#pragma unroll
            for (int c = 0; c < KC; ++c) rs += PT[c][t];
        }
        if (ty < 20) {
            for (int c = 0; c < KC; ++c) {
                float p0 = PT[c][i0+0], p1 = PT[c][i0+1], p2 = PT[c][i0+2], p3 = PT[c][i0+3];
#pragma unroll
                for (int jj = 0; jj < 5; ++jj) {
                    float qv = QT[c][j0+jj];
                    acc[0][jj] += p0*qv; acc[1][jj] += p1*qv;
                    acc[2][jj] += p2*qv; acc[3][jj] += p3*qv;
                }
            }
        }
    }
    __syncthreads();   // all PT/QT reads done; Bsh aliases the same LDS

    // ---- phase 3: write B to LDS, rhs, Jacobi, normalize ----
    float* Bsh = (float*)sm;            // [MQ][MQ+1]
    if (ty < 20) {
#pragma unroll
        for (int a = 0; a < 4; ++a)
#pragma unroll
            for (int jj = 0; jj < 5; ++jj)
                Bsh[(i0+a)*(MQ+1) + j0+jj] = acc[a][jj];
    }
    if (t < MQ) { rh[t] = 1.0f + 0.5f*rs; xs[t] = rh[t]; }
    __syncthreads();
    for (int it = 0; it < 30; ++it) {
        float s = 0.f;
        if (t < MQ) {
            for (int j = 0; j < MQ; ++j) s += Bsh[t*(MQ+1)+j]*xs[j];
        }
        __syncthreads();
        if (t < MQ) xs[t] = rh[t] + 0.25f*s;
        __syncthreads();
    }
    float kv = (t < MQ) ? (xs[t] - 1.0f) : 0.f;
    if (t < 128) {
        float s = kv;
        for (int off = 32; off; off >>= 1) s += __shfl_xor(s, off);
        if ((t & 63) == 0) partial[t >> 6] = s;
    }
    __syncthreads();
    float tot = partial[0] + partial[1];
    if (t < MQ) out[sys*MQ + t] = kv / tot;
}

extern "C" void kernel_launch(void* const* d_in, const int* in_sizes, int n_in,
                              void* d_out, int out_size, void* d_ws, size_t ws_size,
                              hipStream_t stream) {
    const float* sup = (const float*)d_in[0];
    const float* qry = (const float*)d_in[1];
    float* out = (float*)d_out;
    float* ws  = (float*)d_ws;

    float* supmean = ws;                        // 1,280,000 f (layout keeper)
    float* invs    = supmean + 1280000;         // 2,000
    float* invq    = invs + 2000;               // 30,000
    float* Smat    = invq + 30000;              // 15,000,000
    float* m20     = Smat + 15000000;           // 30,000 (unused)
    float* rd20    = m20 + 30000;               // 30,000 (unused)
    float* m10     = rd20 + 30000;              // 150,000 (unused)
    float* rd10    = m10 + 150000;              // 150,000 (unused)
    float* Bm      = rd10 + 150000;             // 3,000,000 (norm partials)
    float* rh      = Bm + 3000000;              // 30,000 (unused)
    ushort* Ahh    = (ushort*)(rh + 30000);     // 19,200,000 u16
    ushort* All    = Ahh + 19200000;            // 19,200,000
    ushort* Bhh    = All + 19200000;            // 1,280,000
    ushort* Bll    = Bhh + 1280000;             // 1,280,000
    float* npq     = Bm;                        // 10 x 30000
    float* nps     = Bm + 300000;               // 10 x 2000

    k_prep<<<dim3(10, 2, BATCH*NQ), 256, 0, stream>>>(qry, Ahh, All, npq, NSYS*HW);
    k_prep_sup<<<dim3(10, 2, BATCH*NWAY), 256, 0, stream>>>(sup, Bhh, Bll, nps);
    k_finishinv<<<(NSYS*HW + BATCH*NWAY*HW + 255)/256, 256, 0, stream>>>(npq, nps, invq, invs);
    k_gemm<<<NWG, 256, 0, stream>>>(Ahh, All, Bhh, Bll, invq, invs, Smat);
    k_post<<<NSYS, 512, 0, stream>>>(Smat, out);
}

// Round 8
// 255.780 us; speedup vs baseline: 1.3810x; 1.3810x over previous
//
#include <hip/hip_runtime.h>
#include <math.h>

#define BATCH 4
#define NSUP 25
#define NQ   75
#define CH   640
#define HW   100
#define NWAY 5
#define KSHOT 5
#define NSYS (BATCH*NQ)   // 300
#define MS   (NWAY*HW)    // 500
#define MQ   HW           // 100
#define MTOT (NQ*HW)      // 7500 rows per batch

typedef __attribute__((ext_vector_type(8))) short bf16x8;
typedef __attribute__((ext_vector_type(4))) float f32x4;

__device__ __forceinline__ ushort f2bf(float f) {
    unsigned u = __float_as_uint(f);
    u += 0x7fff + ((u >> 16) & 1);          // RNE
    return (ushort)(u >> 16);
}
__device__ __forceinline__ float bf2f(ushort h) {
    return __uint_as_float(((unsigned)h) << 16);
}

#define GLD_LDS16(gp, lp) __builtin_amdgcn_global_load_lds( \
    (const __attribute__((address_space(1))) unsigned*)(const void*)(gp), \
    (__attribute__((address_space(3))) unsigned*)(void*)(lp), 16, 0, 0)

// ---------------- K1: transpose + raw bf16 hi/lo split + norm partials (query) ----------------
__global__ __launch_bounds__(256) void k_prep(const float* __restrict__ in,
        ushort* __restrict__ hi, ushort* __restrict__ lo,
        float* __restrict__ normpart, int planesHW) {
    __shared__ float tile[64][65];
    int p  = blockIdx.z;
    int c0 = blockIdx.x * 64;
    int m0 = blockIdx.y * 64;
    int t  = threadIdx.x;
    const float* ib = in + (size_t)p*CH*HW;
#pragma unroll
    for (int i = 0; i < 16; ++i) {
        int l = i*256 + t;
        int cl = l >> 6, ml = l & 63;
        int m = m0 + ml;
        tile[cl][ml] = (m < HW) ? ib[(size_t)(c0+cl)*HW + m] : 0.f;
    }
    __syncthreads();
    if (t < 64 && (m0 + t) < HW) {
        float s = 0.f;
#pragma unroll
        for (int cl = 0; cl < 64; ++cl) { float v = tile[cl][t]; s += v*v; }
        normpart[(size_t)blockIdx.x*planesHW + p*HW + m0 + t] = s;
    }
#pragma unroll
    for (int i = 0; i < 16; ++i) {
        int l = i*256 + t;
        int ml = l >> 6, cl = l & 63;
        int m = m0 + ml;
        if (m < HW) {
            size_t r = (size_t)p*HW + m;
            float v = tile[cl][ml];
            ushort h = f2bf(v);
            float fl = v - bf2f(h);
            hi[r*CH + c0 + cl] = h;
            lo[r*CH + c0 + cl] = f2bf(fl);
        }
    }
}

// ---------------- K1b: support variant — fused 5-shot class mean ----------------
__global__ __launch_bounds__(256) void k_prep_sup(const float* __restrict__ sup,
        ushort* __restrict__ hi, ushort* __restrict__ lo,
        float* __restrict__ normpart) {
    __shared__ float tile[64][65];
    int p  = blockIdx.z;              // b*NWAY + n
    int c0 = blockIdx.x * 64;
    int m0 = blockIdx.y * 64;
    int t  = threadIdx.x;
    int b = p / NWAY, n = p % NWAY;
    const float* ib = sup + ((size_t)(b*NSUP + n*KSHOT))*CH*HW;
#pragma unroll
    for (int i = 0; i < 16; ++i) {
        int l = i*256 + t;
        int cl = l >> 6, ml = l & 63;
        int m = m0 + ml;
        float a = 0.f;
        if (m < HW) {
#pragma unroll
            for (int k = 0; k < KSHOT; ++k)
                a += ib[((size_t)k*CH + c0 + cl)*HW + m];
        }
        tile[cl][ml] = a * 0.2f;
    }
    __syncthreads();
    if (t < 64 && (m0 + t) < HW) {
        float s = 0.f;
#pragma unroll
        for (int cl = 0; cl < 64; ++cl) { float v = tile[cl][t]; s += v*v; }
        normpart[(size_t)blockIdx.x*(BATCH*NWAY*HW) + p*HW + m0 + t] = s;
    }
#pragma unroll
    for (int i = 0; i < 16; ++i) {
        int l = i*256 + t;
        int ml = l >> 6, cl = l & 63;
        int m = m0 + ml;
        if (m < HW) {
            size_t r = (size_t)p*HW + m;
            float v = tile[cl][ml];
            ushort h = f2bf(v);
            float fl = v - bf2f(h);
            hi[r*CH + c0 + cl] = h;
            lo[r*CH + c0 + cl] = f2bf(fl);
        }
    }
}

// ---------------- K2: finish inverse norms (query + support merged) ----------------
__global__ void k_finishinv(const float* __restrict__ pq, const float* __restrict__ ps,
                            float* __restrict__ invq, float* __restrict__ invs) {
    int idx = blockIdx.x * 256 + threadIdx.x;
    if (idx < NSYS*HW) {
        float s = 0.f;
#pragma unroll
        for (int u = 0; u < 10; ++u) s += pq[(size_t)u*(NSYS*HW) + idx];
        invq[idx] = 1.0f / (1e-16f + sqrtf(s));
    } else {
        int j = idx - NSYS*HW;
        if (j < BATCH*NWAY*HW) {
            float s = 0.f;
#pragma unroll
            for (int u = 0; u < 10; ++u) s += ps[(size_t)u*(BATCH*NWAY*HW) + j];
            invs[j] = 1.0f / (1e-16f + sqrtf(s));
        }
    }
}

// ---------------- K3: split-bf16 MFMA GEMM, 128x128 tile, dbuf + counted vmcnt ----------------
#define BM 128
#define BN 128
#define BK 32
#define NKT (CH/BK)           // 20
#define NCT 4
#define NRT 59
#define NWG (NCT*NRT*BATCH)   // 944, divisible by 8
#define BUFB 32768
__global__ __launch_bounds__(256) void k_gemm(
        const ushort* __restrict__ Ah, const ushort* __restrict__ Al,
        const ushort* __restrict__ Bh, const ushort* __restrict__ Bl,
        const float* __restrict__ invq, const float* __restrict__ invs,
        float* __restrict__ S) {
    __shared__ __align__(1024) char lds[65536];
    int hwid = blockIdx.x;
    int l = (hwid & 7) * (NWG/8) + (hwid >> 3);   // chunked XCD swizzle
    int ct = l & 3;
    int rest = l >> 2;            // 0..235
    int rt = rest % NRT;
    int b  = rest / NRT;
    int t  = threadIdx.x;
    int lane = t & 63, w = t >> 6;
    int row0 = rt * BM, col0 = ct * BN;

    const ushort* srcA[4];
    const ushort* srcB[4];
#pragma unroll
    for (int i = 0; i < 4; ++i) {
        int X = i*4096 + t*16;
        int row = X >> 7;
        int sp  = (X >> 4) & 7;
        int s   = sp ^ (row & 7);
        int gr = row0 + row; if (gr > MTOT-1) gr = MTOT-1;
        srcA[i] = ((s & 4) ? Al : Ah) + ((size_t)b*MTOT + gr)*CH + (s & 3)*8;
        int gc = col0 + row; if (gc > MS-1) gc = MS-1;
        srcB[i] = ((s & 4) ? Bl : Bh) + ((size_t)b*MS + gc)*CH + (s & 3)*8;
    }
    int dA = w << 10;

    f32x4 acc[4][4];
#pragma unroll
    for (int mi = 0; mi < 4; ++mi)
#pragma unroll
        for (int ni = 0; ni < 4; ++ni) acc[mi][ni] = (f32x4){0.f,0.f,0.f,0.f};

    int wr = w >> 1, wc = w & 1;
    int q = lane & 15, kg = lane >> 4;

#define STAGE(bufb, kt_) do { \
        int ko = (kt_) * BK; \
        char* bb = lds + (bufb)*BUFB; \
        GLD_LDS16(srcA[0] + ko, bb + 0     + dA); \
        GLD_LDS16(srcA[1] + ko, bb + 4096  + dA); \
        GLD_LDS16(srcA[2] + ko, bb + 8192  + dA); \
        GLD_LDS16(srcA[3] + ko, bb + 12288 + dA); \
        GLD_LDS16(srcB[0] + ko, bb + 16384 + dA); \
        GLD_LDS16(srcB[1] + ko, bb + 20480 + dA); \
        GLD_LDS16(srcB[2] + ko, bb + 24576 + dA); \
        GLD_LDS16(srcB[3] + ko, bb + 28672 + dA); \
    } while (0)

    STAGE(0, 0);
    for (int kt = 0; kt < NKT; ++kt) {
        int cur = kt & 1;
        if (kt + 1 < NKT) {
            STAGE(cur ^ 1, kt + 1);
            asm volatile("s_waitcnt vmcnt(8)" ::: "memory");
        } else {
            asm volatile("s_waitcnt vmcnt(0)" ::: "memory");
        }
        __builtin_amdgcn_sched_barrier(0);
        __builtin_amdgcn_s_barrier();
        __builtin_amdgcn_sched_barrier(0);

        const char* base = lds + cur*BUFB;
        bf16x8 bh[4], bl[4];
#pragma unroll
        for (int ni = 0; ni < 4; ++ni) {
            int colr = wc*64 + ni*16 + q;
            int rb = 16384 + colr*128;
            bh[ni] = *(const bf16x8*)(base + rb + (((kg    ) ^ (colr & 7)) << 4));
            bl[ni] = *(const bf16x8*)(base + rb + (((kg | 4) ^ (colr & 7)) << 4));
        }
#pragma unroll
        for (int mi = 0; mi < 4; ++mi) {
            int rowr = wr*64 + mi*16 + q;
            int rb = rowr*128;
            bf16x8 ah = *(const bf16x8*)(base + rb + (((kg    ) ^ (rowr & 7)) << 4));
            bf16x8 al = *(const bf16x8*)(base + rb + (((kg | 4) ^ (rowr & 7)) << 4));
#pragma unroll
            for (int ni = 0; ni < 4; ++ni) {
                acc[mi][ni] = __builtin_amdgcn_mfma_f32_16x16x32_bf16(ah, bh[ni], acc[mi][ni], 0, 0, 0);
                acc[mi][ni] = __builtin_amdgcn_mfma_f32_16x16x32_bf16(ah, bl[ni], acc[mi][ni], 0, 0, 0);
                acc[mi][ni] = __builtin_amdgcn_mfma_f32_16x16x32_bf16(al, bh[ni], acc[mi][ni], 0, 0, 0);
            }
        }
        __builtin_amdgcn_sched_barrier(0);
        __builtin_amdgcn_s_barrier();
        __builtin_amdgcn_sched_barrier(0);
    }
#undef STAGE

    int colb = col0 + wc*64 + q;
    int rowb = row0 + wr*64 + (kg << 2);
#pragma unroll
    for (int mi = 0; mi < 4; ++mi) {
#pragma unroll
        for (int ni = 0; ni < 4; ++ni) {
            int c = colb + ni*16;
            if (c >= MS) continue;
            float si = invs[b*MS + c];
#pragma unroll
            for (int j = 0; j < 4; ++j) {
                int r = rowb + mi*16 + j;
                if (r < MTOT)
                    S[((size_t)b*MTOT + r)*MS + c] = acc[mi][ni][j] * invq[b*MTOT + r] * si;
            }
        }
    }
}

// ---------------- K4: fused row(g20) + col(g10) softmax stats, 1024 thr ----------------
__global__ __launch_bounds__(1024) void k_stats(const float* __restrict__ S,
        float* __restrict__ m20, float* __restrict__ rd20,
        float* __restrict__ m10, float* __restrict__ rd10) {
    __shared__ float wcm[16][512];
    __shared__ float wcs[16][512];
    int sys = blockIdx.x;
    int t = threadIdx.x;
    int w = t >> 6, l = t & 63;
    const float* Sb = S + (size_t)sys*MQ*MS;
    float colm[8], cols[8];
#pragma unroll
    for (int u = 0; u < 8; ++u) { colm[u] = -1e30f; cols[u] = 0.f; }
    int nu = (l < MS - 448) ? 8 : 7;   // l<52 -> 8 cols
    for (int row = w; row < MQ; row += 16) {
        const float* rp = Sb + (size_t)row*MS;
        float v[8];
        float rm = -1e30f;
#pragma unroll
        for (int u = 0; u < 8; ++u) {
            v[u] = (u < nu) ? rp[l + 64*u] : -1e30f;
            rm = fmaxf(rm, v[u]);
        }
        for (int off = 32; off; off >>= 1) rm = fmaxf(rm, __shfl_xor(rm, off));
        float rs = 0.f;
#pragma unroll
        for (int u = 0; u < 8; ++u) if (u < nu) rs += __expf(20.f*(v[u]-rm));
        for (int off = 32; off; off >>= 1) rs += __shfl_xor(rs, off);
        if (l == 0) { m20[sys*MQ+row] = rm; rd20[sys*MQ+row] = 1.0f/rs; }
#pragma unroll
        for (int u = 0; u < 8; ++u) if (u < nu) {
            float vv = v[u];
            if (vv <= colm[u]) {
                cols[u] += __expf(10.f*(vv - colm[u]));
            } else {
                cols[u] = cols[u]*__expf(10.f*(colm[u]-vv)) + 1.0f;
                colm[u] = vv;
            }
        }
    }
#pragma unroll
    for (int u = 0; u < 8; ++u) { wcm[w][l+64*u] = colm[u]; wcs[w][l+64*u] = cols[u]; }
    __syncthreads();
    if (t < MS) {
        float m = -1e30f;
#pragma unroll
        for (int w2 = 0; w2 < 16; ++w2) m = fmaxf(m, wcm[w2][t]);
        float s = 0.f;
#pragma unroll
        for (int w2 = 0; w2 < 16; ++w2) s += wcs[w2][t]*__expf(10.f*(wcm[w2][t]-m));
        m10[sys*MS+t] = m;
        rd10[sys*MS+t] = 1.0f/s;
    }
}

// ---------------- K5: partial B over a 100-col slice, reg accumulation ----------------
#define KC 50
#define NCH 2
#define NPART 5
#define PADP 102
__global__ __launch_bounds__(256) void k_formB_part(
        const float* __restrict__ S,
        const float* __restrict__ m10, const float* __restrict__ rd10,
        const float* __restrict__ m20, const float* __restrict__ rd20,
        float* __restrict__ Bpart, float* __restrict__ rspart) {
    __shared__ float PT[KC][PADP];   // PT[c][i] = P[i][col0+c]
    __shared__ float QT[KC][PADP];   // QT[c][j] = Q[j][col0+c]
    __shared__ float m20s[MQ], r20s[MQ];
    int part = blockIdx.x;
    int sys  = blockIdx.y;
    int t = threadIdx.x;
    int tx = t % 25, ty = t / 25;
    int j0 = tx*4, i0 = ty*10;
    float acc[10][4] = {};
    float rs = 0.f;
    const float* Sb   = S    + (size_t)sys*MQ*MS;
    const float* m10b = m10  + sys*MS;
    const float* r10b = rd10 + sys*MS;
    if (t < MQ) { m20s[t] = m20[sys*MQ+t]; r20s[t] = rd20[sys*MQ+t]; }

    for (int sub = 0; sub < NCH; ++sub) {
        int col0 = part*(KC*NCH) + sub*KC;
        __syncthreads();
        for (int ll = t; ll < MQ*KC; ll += 256) {
            int r = ll / KC, c = ll % KC;
            float v = Sb[(size_t)r*MS + col0 + c];
            PT[c][r] = __expf(10.f*(v - m10b[col0+c])) * r10b[col0+c];
            QT[c][r] = __expf(20.f*(v - m20s[r])) * r20s[r];
        }
        __syncthreads();
        if (t < MQ) {
#pragma unroll
            for (int c = 0; c < KC; ++c) rs += PT[c][t];
        }
        if (ty < 10) {
            for (int c = 0; c < KC; ++c) {
                float2 q01 = *(const float2*)&QT[c][j0];
                float2 q23 = *(const float2*)&QT[c][j0+2];
                float2 p[5];
#pragma unroll
                for (int u = 0; u < 5; ++u) p[u] = *(const float2*)&PT[c][i0+2*u];
#pragma unroll
                for (int u = 0; u < 5; ++u) {
                    acc[2*u  ][0] += p[u].x*q01.x; acc[2*u  ][1] += p[u].x*q01.y;
                    acc[2*u  ][2] += p[u].x*q23.x; acc[2*u  ][3] += p[u].x*q23.y;
                    acc[2*u+1][0] += p[u].y*q01.x; acc[2*u+1][1] += p[u].y*q01.y;
                    acc[2*u+1][2] += p[u].y*q23.x; acc[2*u+1][3] += p[u].y*q23.y;
                }
            }
        }
    }
    if (ty < 10) {
        float* Bp = Bpart + ((size_t)part*NSYS + sys)*(MQ*MQ);
#pragma unroll
        for (int ii = 0; ii < 10; ++ii) {
            float4 v = make_float4(acc[ii][0], acc[ii][1], acc[ii][2], acc[ii][3]);
            *(float4*)&Bp[(i0+ii)*MQ + j0] = v;
        }
    }
    if (t < MQ) rspart[((size_t)part*NSYS + sys)*MQ + t] = rs;
}

// ---------------- K6: sum partials, Jacobi solve (I - 0.25 B) x = rhs, normalize ----------------
__global__ __launch_bounds__(256) void k_solve(
        const float* __restrict__ Bpart, const float* __restrict__ rspart,
        float* __restrict__ out) {
    __shared__ float Bsh[MQ][MQ+1];
    __shared__ float xs[MQ];
    __shared__ float rh[MQ];
    __shared__ float partial[4];
    int sys = blockIdx.x;
    int t = threadIdx.x;
    for (int ll = t; ll < MQ*MQ; ll += 256) {
        float s = 0.f;
#pragma unroll
        for (int p = 0; p < NPART; ++p)
            s += Bpart[((size_t)p*NSYS + sys)*(MQ*MQ) + ll];
        Bsh[ll/MQ][ll%MQ] = s;
    }
    if (t < MQ) {
        float rsum = 0.f;
#pragma unroll
        for (int p = 0; p < NPART; ++p)
            rsum += rspart[((size_t)p*NSYS + sys)*MQ + t];
        rh[t] = 1.0f + 0.5f*rsum;
        xs[t] = rh[t];
    }
    __syncthreads();
    for (int it = 0; it < 16; ++it) {
        float s = 0.f;
        if (t < MQ) {
            for (int j = 0; j < MQ; ++j) s += Bsh[t][j]*xs[j];
        }
        __syncthreads();
        if (t < MQ) xs[t] = rh[t] + 0.25f*s;
        __syncthreads();
    }
    float kv = (t < MQ) ? (xs[t] - 1.0f) : 0.f;
    float s = kv;
    for (int off = 32; off; off >>= 1) s += __shfl_xor(s, off);
    if ((t & 63) == 0) partial[t >> 6] = s;
    __syncthreads();
    float tot = partial[0] + partial[1] + partial[2] + partial[3];
    if (t < MQ) out[sys*MQ + t] = kv / tot;
}

extern "C" void kernel_launch(void* const* d_in, const int* in_sizes, int n_in,
                              void* d_out, int out_size, void* d_ws, size_t ws_size,
                              hipStream_t stream) {
    const float* sup = (const float*)d_in[0];
    const float* qry = (const float*)d_in[1];
    float* out = (float*)d_out;
    float* ws  = (float*)d_ws;

    float* supmean = ws;                        // 1,280,000 f (layout keeper)
    float* invs    = supmean + 1280000;         // 2,000
    float* invq    = invs + 2000;               // 30,000
    float* Smat    = invq + 30000;              // 15,000,000
    float* m20     = Smat + 15000000;           // 30,000
    float* rd20    = m20 + 30000;               // 30,000
    float* m10     = rd20 + 30000;              // 150,000
    float* rd10    = m10 + 150000;              // 150,000
    float* Bm      = rd10 + 150000;             // 3,000,000 (norm partials)
    float* rh      = Bm + 3000000;              // 30,000 (unused)
    ushort* Ahh    = (ushort*)(rh + 30000);     // 19,200,000 u16
    ushort* All    = Ahh + 19200000;            // 19,200,000
    ushort* Bhh    = All + 19200000;            // 1,280,000
    ushort* Bll    = Bhh + 1280000;             // 1,280,000
    float* npq     = Bm;                        // 10 x 30000
    float* nps     = Bm + 300000;               // 10 x 2000
    float* Bpart   = (float*)Ahh;               // 15,000,000 f (aliases dead A-split)
    float* rspart  = Bpart + 15000000;          // 150,000 f

    k_prep<<<dim3(10, 2, BATCH*NQ), 256, 0, stream>>>(qry, Ahh, All, npq, NSYS*HW);
    k_prep_sup<<<dim3(10, 2, BATCH*NWAY), 256, 0, stream>>>(sup, Bhh, Bll, nps);
    k_finishinv<<<(NSYS*HW + BATCH*NWAY*HW + 255)/256, 256, 0, stream>>>(npq, nps, invq, invs);
    k_gemm<<<NWG, 256, 0, stream>>>(Ahh, All, Bhh, Bll, invq, invs, Smat);
    k_stats<<<NSYS, 1024, 0, stream>>>(Smat, m20, rd20, m10, rd10);
    k_formB_part<<<dim3(NPART, NSYS), 256, 0, stream>>>(Smat, m10, rd10, m20, rd20, Bpart, rspart);
    k_solve<<<NSYS, 256, 0, stream>>>(Bpart, rspart, out);
}

// Round 9
// 197.962 us; speedup vs baseline: 1.7844x; 1.2921x over previous
//
#include <hip/hip_runtime.h>
#include <math.h>

#define BATCH 4
#define NSUP 25
#define NQ   75
#define CH   640
#define HW   100
#define NWAY 5
#define KSHOT 5
#define NSYS (BATCH*NQ)   // 300
#define MS   (NWAY*HW)    // 500
#define MQ   HW           // 100
#define MTOT (NQ*HW)      // 7500 rows per batch

typedef __attribute__((ext_vector_type(8))) short bf16x8;
typedef __attribute__((ext_vector_type(4))) float f32x4;
typedef __attribute__((ext_vector_type(16))) float f32x16;
typedef __attribute__((ext_vector_type(4))) short s16x4;

__device__ __forceinline__ ushort f2bf(float f) {
    unsigned u = __float_as_uint(f);
    u += 0x7fff + ((u >> 16) & 1);          // RNE
    return (ushort)(u >> 16);
}
__device__ __forceinline__ float bf2f(ushort h) {
    return __uint_as_float(((unsigned)h) << 16);
}

#define GLD_LDS16(gp, lp) __builtin_amdgcn_global_load_lds( \
    (const __attribute__((address_space(1))) unsigned*)(const void*)(gp), \
    (__attribute__((address_space(3))) unsigned*)(void*)(lp), 16, 0, 0)

// ---------------- K1: transpose + raw bf16 hi/lo split + norm partials (query) ----------------
__global__ __launch_bounds__(256) void k_prep(const float* __restrict__ in,
        ushort* __restrict__ hi, ushort* __restrict__ lo,
        float* __restrict__ normpart, int planesHW) {
    __shared__ float tile[64][65];
    int p  = blockIdx.z;
    int c0 = blockIdx.x * 64;
    int m0 = blockIdx.y * 64;
    int t  = threadIdx.x;
    const float* ib = in + (size_t)p*CH*HW;
#pragma unroll
    for (int i = 0; i < 16; ++i) {
        int l = i*256 + t;
        int cl = l >> 6, ml = l & 63;
        int m = m0 + ml;
        tile[cl][ml] = (m < HW) ? ib[(size_t)(c0+cl)*HW + m] : 0.f;
    }
    __syncthreads();
    if (t < 64 && (m0 + t) < HW) {
        float s = 0.f;
#pragma unroll
        for (int cl = 0; cl < 64; ++cl) { float v = tile[cl][t]; s += v*v; }
        normpart[(size_t)blockIdx.x*planesHW + p*HW + m0 + t] = s;
    }
#pragma unroll
    for (int i = 0; i < 16; ++i) {
        int l = i*256 + t;
        int ml = l >> 6, cl = l & 63;
        int m = m0 + ml;
        if (m < HW) {
            size_t r = (size_t)p*HW + m;
            float v = tile[cl][ml];
            ushort h = f2bf(v);
            float fl = v - bf2f(h);
            hi[r*CH + c0 + cl] = h;
            lo[r*CH + c0 + cl] = f2bf(fl);
        }
    }
}

// ---------------- K1b: support variant — fused 5-shot class mean ----------------
__global__ __launch_bounds__(256) void k_prep_sup(const float* __restrict__ sup,
        ushort* __restrict__ hi, ushort* __restrict__ lo,
        float* __restrict__ normpart) {
    __shared__ float tile[64][65];
    int p  = blockIdx.z;              // b*NWAY + n
    int c0 = blockIdx.x * 64;
    int m0 = blockIdx.y * 64;
    int t  = threadIdx.x;
    int b = p / NWAY, n = p % NWAY;
    const float* ib = sup + ((size_t)(b*NSUP + n*KSHOT))*CH*HW;
#pragma unroll
    for (int i = 0; i < 16; ++i) {
        int l = i*256 + t;
        int cl = l >> 6, ml = l & 63;
        int m = m0 + ml;
        float a = 0.f;
        if (m < HW) {
#pragma unroll
            for (int k = 0; k < KSHOT; ++k)
                a += ib[((size_t)k*CH + c0 + cl)*HW + m];
        }
        tile[cl][ml] = a * 0.2f;
    }
    __syncthreads();
    if (t < 64 && (m0 + t) < HW) {
        float s = 0.f;
#pragma unroll
        for (int cl = 0; cl < 64; ++cl) { float v = tile[cl][t]; s += v*v; }
        normpart[(size_t)blockIdx.x*(BATCH*NWAY*HW) + p*HW + m0 + t] = s;
    }
#pragma unroll
    for (int i = 0; i < 16; ++i) {
        int l = i*256 + t;
        int ml = l >> 6, cl = l & 63;
        int m = m0 + ml;
        if (m < HW) {
            size_t r = (size_t)p*HW + m;
            float v = tile[cl][ml];
            ushort h = f2bf(v);
            float fl = v - bf2f(h);
            hi[r*CH + c0 + cl] = h;
            lo[r*CH + c0 + cl] = f2bf(fl);
        }
    }
}

// ---------------- K2: finish inverse norms (query + support merged) ----------------
__global__ void k_finishinv(const float* __restrict__ pq, const float* __restrict__ ps,
                            float* __restrict__ invq, float* __restrict__ invs) {
    int idx = blockIdx.x * 256 + threadIdx.x;
    if (idx < NSYS*HW) {
        float s = 0.f;
#pragma unroll
        for (int u = 0; u < 10; ++u) s += pq[(size_t)u*(NSYS*HW) + idx];
        invq[idx] = 1.0f / (1e-16f + sqrtf(s));
    } else {
        int j = idx - NSYS*HW;
        if (j < BATCH*NWAY*HW) {
            float s = 0.f;
#pragma unroll
            for (int u = 0; u < 10; ++u) s += ps[(size_t)u*(BATCH*NWAY*HW) + j];
            invs[j] = 1.0f / (1e-16f + sqrtf(s));
        }
    }
}

// ---------------- K3: split-bf16 MFMA GEMM, 128x128 tile, dbuf + counted vmcnt ----------------
#define BM 128
#define BN 128
#define BK 32
#define NKT (CH/BK)           // 20
#define NCT 4
#define NRT 59
#define NWG (NCT*NRT*BATCH)   // 944, divisible by 8
#define BUFB 32768
__global__ __launch_bounds__(256) void k_gemm(
        const ushort* __restrict__ Ah, const ushort* __restrict__ Al,
        const ushort* __restrict__ Bh, const ushort* __restrict__ Bl,
        const float* __restrict__ invq, const float* __restrict__ invs,
        float* __restrict__ S) {
    __shared__ __align__(1024) char lds[65536];
    int hwid = blockIdx.x;
    int l = (hwid & 7) * (NWG/8) + (hwid >> 3);   // chunked XCD swizzle
    int ct = l & 3;
    int rest = l >> 2;            // 0..235
    int rt = rest % NRT;
    int b  = rest / NRT;
    int t  = threadIdx.x;
    int lane = t & 63, w = t >> 6;
    int row0 = rt * BM, col0 = ct * BN;

    const ushort* srcA[4];
    const ushort* srcB[4];
#pragma unroll
    for (int i = 0; i < 4; ++i) {
        int X = i*4096 + t*16;
        int row = X >> 7;
        int sp  = (X >> 4) & 7;
        int s   = sp ^ (row & 7);
        int gr = row0 + row; if (gr > MTOT-1) gr = MTOT-1;
        srcA[i] = ((s & 4) ? Al : Ah) + ((size_t)b*MTOT + gr)*CH + (s & 3)*8;
        int gc = col0 + row; if (gc > MS-1) gc = MS-1;
        srcB[i] = ((s & 4) ? Bl : Bh) + ((size_t)b*MS + gc)*CH + (s & 3)*8;
    }
    int dA = w << 10;

    f32x4 acc[4][4];
#pragma unroll
    for (int mi = 0; mi < 4; ++mi)
#pragma unroll
        for (int ni = 0; ni < 4; ++ni) acc[mi][ni] = (f32x4){0.f,0.f,0.f,0.f};

    int wr = w >> 1, wc = w & 1;
    int q = lane & 15, kg = lane >> 4;

#define STAGE(bufb, kt_) do { \
        int ko = (kt_) * BK; \
        char* bb = lds + (bufb)*BUFB; \
        GLD_LDS16(srcA[0] + ko, bb + 0     + dA); \
        GLD_LDS16(srcA[1] + ko, bb + 4096  + dA); \
        GLD_LDS16(srcA[2] + ko, bb + 8192  + dA); \
        GLD_LDS16(srcA[3] + ko, bb + 12288 + dA); \
        GLD_LDS16(srcB[0] + ko, bb + 16384 + dA); \
        GLD_LDS16(srcB[1] + ko, bb + 20480 + dA); \
        GLD_LDS16(srcB[2] + ko, bb + 24576 + dA); \
        GLD_LDS16(srcB[3] + ko, bb + 28672 + dA); \
    } while (0)

    STAGE(0, 0);
    for (int kt = 0; kt < NKT; ++kt) {
        int cur = kt & 1;
        if (kt + 1 < NKT) {
            STAGE(cur ^ 1, kt + 1);
            asm volatile("s_waitcnt vmcnt(8)" ::: "memory");
        } else {
            asm volatile("s_waitcnt vmcnt(0)" ::: "memory");
        }
        __builtin_amdgcn_sched_barrier(0);
        __builtin_amdgcn_s_barrier();
        __builtin_amdgcn_sched_barrier(0);

        const char* base = lds + cur*BUFB;
        bf16x8 bh[4], bl[4];
#pragma unroll
        for (int ni = 0; ni < 4; ++ni) {
            int colr = wc*64 + ni*16 + q;
            int rb = 16384 + colr*128;
            bh[ni] = *(const bf16x8*)(base + rb + (((kg    ) ^ (colr & 7)) << 4));
            bl[ni] = *(const bf16x8*)(base + rb + (((kg | 4) ^ (colr & 7)) << 4));
        }
#pragma unroll
        for (int mi = 0; mi < 4; ++mi) {
            int rowr = wr*64 + mi*16 + q;
            int rb = rowr*128;
            bf16x8 ah = *(const bf16x8*)(base + rb + (((kg    ) ^ (rowr & 7)) << 4));
            bf16x8 al = *(const bf16x8*)(base + rb + (((kg | 4) ^ (rowr & 7)) << 4));
#pragma unroll
            for (int ni = 0; ni < 4; ++ni) {
                acc[mi][ni] = __builtin_amdgcn_mfma_f32_16x16x32_bf16(ah, bh[ni], acc[mi][ni], 0, 0, 0);
                acc[mi][ni] = __builtin_amdgcn_mfma_f32_16x16x32_bf16(ah, bl[ni], acc[mi][ni], 0, 0, 0);
                acc[mi][ni] = __builtin_amdgcn_mfma_f32_16x16x32_bf16(al, bh[ni], acc[mi][ni], 0, 0, 0);
            }
        }
        __builtin_amdgcn_sched_barrier(0);
        __builtin_amdgcn_s_barrier();
        __builtin_amdgcn_sched_barrier(0);
    }
#undef STAGE

    int colb = col0 + wc*64 + q;
    int rowb = row0 + wr*64 + (kg << 2);
#pragma unroll
    for (int mi = 0; mi < 4; ++mi) {
#pragma unroll
        for (int ni = 0; ni < 4; ++ni) {
            int c = colb + ni*16;
            if (c >= MS) continue;
            float si = invs[b*MS + c];
#pragma unroll
            for (int j = 0; j < 4; ++j) {
                int r = rowb + mi*16 + j;
                if (r < MTOT)
                    S[((size_t)b*MTOT + r)*MS + c] = acc[mi][ni][j] * invq[b*MTOT + r] * si;
            }
        }
    }
}

// ---------------- K4: fused row(g20) + col(g10) softmax stats, 1024 thr ----------------
__global__ __launch_bounds__(1024) void k_stats(const float* __restrict__ S,
        float* __restrict__ m20, float* __restrict__ rd20,
        float* __restrict__ m10, float* __restrict__ rd10) {
    __shared__ float wcm[16][512];
    __shared__ float wcs[16][512];
    int sys = blockIdx.x;
    int t = threadIdx.x;
    int w = t >> 6, l = t & 63;
    const float* Sb = S + (size_t)sys*MQ*MS;
    float colm[8], cols[8];
#pragma unroll
    for (int u = 0; u < 8; ++u) { colm[u] = -1e30f; cols[u] = 0.f; }
    int nu = (l < MS - 448) ? 8 : 7;   // l<52 -> 8 cols
    for (int row = w; row < MQ; row += 16) {
        const float* rp = Sb + (size_t)row*MS;
        float v[8];
        float rm = -1e30f;
#pragma unroll
        for (int u = 0; u < 8; ++u) {
            v[u] = (u < nu) ? rp[l + 64*u] : -1e30f;
            rm = fmaxf(rm, v[u]);
        }
        for (int off = 32; off; off >>= 1) rm = fmaxf(rm, __shfl_xor(rm, off));
        float rs = 0.f;
#pragma unroll
        for (int u = 0; u < 8; ++u) if (u < nu) rs += __expf(20.f*(v[u]-rm));
        for (int off = 32; off; off >>= 1) rs += __shfl_xor(rs, off);
        if (l == 0) { m20[sys*MQ+row] = rm; rd20[sys*MQ+row] = 1.0f/rs; }
#pragma unroll
        for (int u = 0; u < 8; ++u) if (u < nu) {
            float vv = v[u];
            if (vv <= colm[u]) {
                cols[u] += __expf(10.f*(vv - colm[u]));
            } else {
                cols[u] = cols[u]*__expf(10.f*(colm[u]-vv)) + 1.0f;
                colm[u] = vv;
            }
        }
    }
#pragma unroll
    for (int u = 0; u < 8; ++u) { wcm[w][l+64*u] = colm[u]; wcs[w][l+64*u] = cols[u]; }
    __syncthreads();
    if (t < MS) {
        float m = -1e30f;
#pragma unroll
        for (int w2 = 0; w2 < 16; ++w2) m = fmaxf(m, wcm[w2][t]);
        float s = 0.f;
#pragma unroll
        for (int w2 = 0; w2 < 16; ++w2) s += wcs[w2][t]*__expf(10.f*(wcm[w2][t]-m));
        m10[sys*MS+t] = m;
        rd10[sys*MS+t] = 1.0f/s;
    }
}

// ---------------- K5: fused MFMA formB + Jacobi solve + normalize, one block/sys ----------------
// B = P·Q^T via mfma_32x32x16_bf16, M=N=128 pad (valid 100), K=512 pad (valid 500).
// Q gets an appended ones-column at n=100 so rhs rowsum falls out of the MFMA.
// LDS PT/QT: [128 rows][128 c] bf16, 256B rows, 16B-slot XOR s^(row&15) -> 2-way reads.
__global__ __launch_bounds__(256) void k_fsolve(const float* __restrict__ S,
        const float* __restrict__ m10, const float* __restrict__ rd10,
        const float* __restrict__ m20, const float* __restrict__ rd20,
        float* __restrict__ out) {
    __shared__ __align__(16) char PQ[65536];        // PT [0,32K), QT [32K,64K); Bsh aliases
    __shared__ __align__(16) float m10s[MS], r10s[MS];
    __shared__ float m20s[MQ], r20s[MQ];
    __shared__ float xs[MQ], rh[MQ];
    __shared__ float partial[2];
    int sys = blockIdx.x;
    int t = threadIdx.x;
    int l = t & 63, w = t >> 6;
    const float* Sb = S + (size_t)sys*MQ*MS;
    char* PT = PQ;
    char* QT = PQ + 32768;

    for (int c = t; c < MS; c += 256) { m10s[c] = m10[sys*MS+c]; r10s[c] = rd10[sys*MS+c]; }
    if (t < MQ) { m20s[t] = m20[sys*MQ+t]; r20s[t] = rd20[sys*MQ+t]; }
    __syncthreads();

    int i = t >> 1, h = t & 1;
    int ccb = h*64;
    float m20i = 0.f, r20i = 0.f;
    if (i < MQ) { m20i = m20s[i]; r20i = r20s[i]; }

    f32x16 acc[4];
#pragma unroll
    for (int nt = 0; nt < 4; ++nt)
#pragma unroll
        for (int rg = 0; rg < 16; ++rg) acc[nt][rg] = 0.f;

    int rA = l & 31;
    int grA = w*32 + rA;          // A row this lane reads
    int kg = l >> 5;

    for (int ck = 0; ck < 4; ++ck) {
        int c0 = ck*128;
        __syncthreads();          // previous chunk's tiles fully consumed
        // ---- stage P/Q bf16 tiles ----
        if (i < MQ) {
            const float* sr = Sb + (size_t)i*MS;
#pragma unroll
            for (int j = 0; j < 16; ++j) {
                int cc = ccb + 4*j;
                int cg = c0 + cc;
                int phys = i*256 + ((((cc>>3) ^ (i&15)))<<4) + ((cc&7)*2);
                s16x4 pv, qv;
                if (cg < MS) {
                    float4 v  = *(const float4*)(sr + cg);
                    float4 m1 = *(const float4*)&m10s[cg];
                    float4 r1 = *(const float4*)&r10s[cg];
                    pv.x = (short)f2bf(__expf(10.f*(v.x - m1.x))*r1.x);
                    pv.y = (short)f2bf(__expf(10.f*(v.y - m1.y))*r1.y);
                    pv.z = (short)f2bf(__expf(10.f*(v.z - m1.z))*r1.z);
                    pv.w = (short)f2bf(__expf(10.f*(v.w - m1.w))*r1.w);
                    qv.x = (short)f2bf(__expf(20.f*(v.x - m20i))*r20i);
                    qv.y = (short)f2bf(__expf(20.f*(v.y - m20i))*r20i);
                    qv.z = (short)f2bf(__expf(20.f*(v.z - m20i))*r20i);
                    qv.w = (short)f2bf(__expf(20.f*(v.w - m20i))*r20i);
                } else {
                    pv = (s16x4){0,0,0,0}; qv = (s16x4){0,0,0,0};
                }
                *(s16x4*)(PT + phys) = pv;
                *(s16x4*)(QT + phys) = qv;
            }
        } else {
            short one = (short)0x3F80;
#pragma unroll
            for (int j = 0; j < 16; ++j) {
                int cc = ccb + 4*j;
                int cg = c0 + cc;
                int phys = i*256 + ((((cc>>3) ^ (i&15)))<<4) + ((cc&7)*2);
                s16x4 z = (s16x4){0,0,0,0};
                s16x4 qv = z;
                if (i == MQ && cg < MS) qv = (s16x4){one, one, one, one};  // ones col block (row 100 of Q)
                *(s16x4*)(PT + phys) = z;
                *(s16x4*)(QT + phys) = qv;
            }
        }
        __syncthreads();
        // ---- MFMA over this 128-c chunk: 8 k-iters of 16 ----
#pragma unroll
        for (int kk = 0; kk < 8; ++kk) {
            int sA = (kk*2 + kg) ^ (grA & 15);
            bf16x8 af = *(const bf16x8*)(PT + grA*256 + (sA<<4));
#pragma unroll
            for (int nt = 0; nt < 4; ++nt) {
                int gc = nt*32 + (l & 31);
                int sB = (kk*2 + kg) ^ (gc & 15);
                bf16x8 bfr = *(const bf16x8*)(QT + gc*256 + (sB<<4));
                acc[nt] = __builtin_amdgcn_mfma_f32_32x32x16_bf16(af, bfr, acc[nt], 0, 0, 0);
            }
        }
    }
    __syncthreads();

    // ---- write B (+rhs col) to LDS; stride 101 floats => conflict-free matvec ----
    float* Bsh = (float*)PQ;          // [100][101], 40.4 KB, aliases PT/QT
#pragma unroll
    for (int nt = 0; nt < 4; ++nt) {
        int col = nt*32 + (l & 31);
        if (col > MQ) continue;       // keep cols 0..100 (100 = rhs)
#pragma unroll
        for (int rg = 0; rg < 16; ++rg) {
            int row = w*32 + (rg & 3) + 8*(rg >> 2) + 4*(l >> 5);
            if (row < MQ) Bsh[row*101 + col] = acc[nt][rg];
        }
    }
    __syncthreads();
    if (t < MQ) { rh[t] = 1.0f + 0.5f*Bsh[t*101 + 100]; xs[t] = rh[t]; }
    __syncthreads();
    // ---- Jacobi: x <- rh + 0.25 B x  (rho <= 0.25, 16 iters => ~2e-10) ----
    for (int it = 0; it < 16; ++it) {
        float s = 0.f;
        if (t < MQ) {
            for (int j = 0; j < MQ; ++j) s += Bsh[t*101 + j]*xs[j];
        }
        __syncthreads();
        if (t < MQ) xs[t] = rh[t] + 0.25f*s;
        __syncthreads();
    }
    float kv = (t < MQ) ? (xs[t] - 1.0f) : 0.f;
    if (t < 128) {
        float s = kv;
        for (int off = 32; off; off >>= 1) s += __shfl_xor(s, off);
        if ((t & 63) == 0) partial[t >> 6] = s;
    }
    __syncthreads();
    float tot = partial[0] + partial[1];
    if (t < MQ) out[sys*MQ + t] = kv / tot;
}

extern "C" void kernel_launch(void* const* d_in, const int* in_sizes, int n_in,
                              void* d_out, int out_size, void* d_ws, size_t ws_size,
                              hipStream_t stream) {
    const float* sup = (const float*)d_in[0];
    const float* qry = (const float*)d_in[1];
    float* out = (float*)d_out;
    float* ws  = (float*)d_ws;

    float* supmean = ws;                        // 1,280,000 f (layout keeper)
    float* invs    = supmean + 1280000;         // 2,000
    float* invq    = invs + 2000;               // 30,000
    float* Smat    = invq + 30000;              // 15,000,000
    float* m20     = Smat + 15000000;           // 30,000
    float* rd20    = m20 + 30000;               // 30,000
    float* m10     = rd20 + 30000;              // 150,000
    float* rd10    = m10 + 150000;              // 150,000
    float* Bm      = rd10 + 150000;             // 3,000,000 (norm partials)
    float* rh      = Bm + 3000000;              // 30,000 (unused)
    ushort* Ahh    = (ushort*)(rh + 30000);     // 19,200,000 u16
    ushort* All    = Ahh + 19200000;            // 19,200,000
    ushort* Bhh    = All + 19200000;            // 1,280,000
    ushort* Bll    = Bhh + 1280000;             // 1,280,000
    float* npq     = Bm;                        // 10 x 30000
    float* nps     = Bm + 300000;               // 10 x 2000

    k_prep<<<dim3(10, 2, BATCH*NQ), 256, 0, stream>>>(qry, Ahh, All, npq, NSYS*HW);
    k_prep_sup<<<dim3(10, 2, BATCH*NWAY), 256, 0, stream>>>(sup, Bhh, Bll, nps);
    k_finishinv<<<(NSYS*HW + BATCH*NWAY*HW + 255)/256, 256, 0, stream>>>(npq, nps, invq, invs);
    k_gemm<<<NWG, 256, 0, stream>>>(Ahh, All, Bhh, Bll, invq, invs, Smat);
    k_stats<<<NSYS, 1024, 0, stream>>>(Smat, m20, rd20, m10, rd10);
    k_fsolve<<<NSYS, 256, 0, stream>>>(Smat, m10, rd10, m20, rd20, out);
}

// Round 10
// 197.008 us; speedup vs baseline: 1.7930x; 1.0048x over previous
//
#include <hip/hip_runtime.h>
#include <math.h>

#define BATCH 4
#define NSUP 25
#define NQ   75
#define CH   640
#define HW   100
#define NWAY 5
#define KSHOT 5
#define NSYS (BATCH*NQ)   // 300
#define MS   (NWAY*HW)    // 500
#define MQ   HW           // 100
#define MTOT (NQ*HW)      // 7500 rows per batch

typedef __attribute__((ext_vector_type(8))) short bf16x8;
typedef __attribute__((ext_vector_type(4))) float f32x4;
typedef __attribute__((ext_vector_type(16))) float f32x16;
typedef __attribute__((ext_vector_type(4))) short s16x4;

__device__ __forceinline__ ushort f2bf(float f) {
    unsigned u = __float_as_uint(f);
    u += 0x7fff + ((u >> 16) & 1);          // RNE
    return (ushort)(u >> 16);
}
__device__ __forceinline__ float bf2f(ushort h) {
    return __uint_as_float(((unsigned)h) << 16);
}

#define GLD_LDS16(gp, lp) __builtin_amdgcn_global_load_lds( \
    (const __attribute__((address_space(1))) unsigned*)(const void*)(gp), \
    (__attribute__((address_space(3))) unsigned*)(void*)(lp), 16, 0, 0)

// ---------------- K1: transpose + raw bf16 hi/lo split + norm partials ----------------
// z < 300: query plane; z >= 300: support class (fused 5-shot mean)
__global__ __launch_bounds__(256) void k_prep_all(
        const float* __restrict__ qry, const float* __restrict__ sup,
        ushort* __restrict__ qhi, ushort* __restrict__ qlo,
        ushort* __restrict__ shi, ushort* __restrict__ slo,
        float* __restrict__ npq, float* __restrict__ nps) {
    __shared__ float tile[64][65];
    int z  = blockIdx.z;
    int c0 = blockIdx.x * 64;
    int m0 = blockIdx.y * 64;
    int t  = threadIdx.x;
    bool isq = (z < BATCH*NQ);
    int p = isq ? z : (z - BATCH*NQ);          // plane index within its family
    ushort* hi; ushort* lo; float* normpart; int planesHW;
    if (isq) { hi = qhi; lo = qlo; normpart = npq; planesHW = NSYS*HW; }
    else     { hi = shi; lo = slo; normpart = nps; planesHW = BATCH*NWAY*HW; }

    if (isq) {
        const float* ib = qry + (size_t)p*CH*HW;
#pragma unroll
        for (int i = 0; i < 16; ++i) {
            int l = i*256 + t;
            int cl = l >> 6, ml = l & 63;
            int m = m0 + ml;
            tile[cl][ml] = (m < HW) ? ib[(size_t)(c0+cl)*HW + m] : 0.f;
        }
    } else {
        int b = p / NWAY, n = p % NWAY;
        const float* ib = sup + ((size_t)(b*NSUP + n*KSHOT))*CH*HW;
#pragma unroll
        for (int i = 0; i < 16; ++i) {
            int l = i*256 + t;
            int cl = l >> 6, ml = l & 63;
            int m = m0 + ml;
            float a = 0.f;
            if (m < HW) {
#pragma unroll
                for (int k = 0; k < KSHOT; ++k)
                    a += ib[((size_t)k*CH + c0 + cl)*HW + m];
            }
            tile[cl][ml] = a * 0.2f;
        }
    }
    __syncthreads();
    if (t < 64 && (m0 + t) < HW) {
        float s = 0.f;
#pragma unroll
        for (int cl = 0; cl < 64; ++cl) { float v = tile[cl][t]; s += v*v; }
        normpart[(size_t)blockIdx.x*planesHW + p*HW + m0 + t] = s;
    }
#pragma unroll
    for (int i = 0; i < 16; ++i) {
        int l = i*256 + t;
        int ml = l >> 6, cl = l & 63;
        int m = m0 + ml;
        if (m < HW) {
            size_t r = (size_t)p*HW + m;
            float v = tile[cl][ml];
            ushort h = f2bf(v);
            float fl = v - bf2f(h);
            hi[r*CH + c0 + cl] = h;
            lo[r*CH + c0 + cl] = f2bf(fl);
        }
    }
}

// ---------------- K2: finish inverse norms (query + support merged) ----------------
__global__ void k_finishinv(const float* __restrict__ pq, const float* __restrict__ ps,
                            float* __restrict__ invq, float* __restrict__ invs) {
    int idx = blockIdx.x * 256 + threadIdx.x;
    if (idx < NSYS*HW) {
        float s = 0.f;
#pragma unroll
        for (int u = 0; u < 10; ++u) s += pq[(size_t)u*(NSYS*HW) + idx];
        invq[idx] = 1.0f / (1e-16f + sqrtf(s));
    } else {
        int j = idx - NSYS*HW;
        if (j < BATCH*NWAY*HW) {
            float s = 0.f;
#pragma unroll
            for (int u = 0; u < 10; ++u) s += ps[(size_t)u*(BATCH*NWAY*HW) + j];
            invs[j] = 1.0f / (1e-16f + sqrtf(s));
        }
    }
}

// ---------------- K3: split-bf16 MFMA GEMM, 128x128 tile, single 32KB buffer ----------------
// m97 structure: stage -> vmcnt(0)+barrier -> compute -> barrier; occupancy does the
// overlap (5 blocks/CU: LDS 32KB, VGPR<=102).
#define BM 128
#define BN 128
#define BK 32
#define NKT (CH/BK)           // 20
#define NCT 4
#define NRT 59
#define NWG (NCT*NRT*BATCH)   // 944, divisible by 8
__global__ __launch_bounds__(256) void k_gemm(
        const ushort* __restrict__ Ah, const ushort* __restrict__ Al,
        const ushort* __restrict__ Bh, const ushort* __restrict__ Bl,
        const float* __restrict__ invq, const float* __restrict__ invs,
        float* __restrict__ S) {
    __shared__ __align__(1024) char lds[32768];
    int hwid = blockIdx.x;
    int l = (hwid & 7) * (NWG/8) + (hwid >> 3);   // chunked XCD swizzle
    int ct = l & 3;
    int rest = l >> 2;            // 0..235
    int rt = rest % NRT;
    int b  = rest / NRT;
    int t  = threadIdx.x;
    int lane = t & 63, w = t >> 6;
    int row0 = rt * BM, col0 = ct * BN;

    const ushort* srcA[4];
    const ushort* srcB[4];
#pragma unroll
    for (int i = 0; i < 4; ++i) {
        int X = i*4096 + t*16;
        int row = X >> 7;
        int sp  = (X >> 4) & 7;
        int s   = sp ^ (row & 7);
        int gr = row0 + row; if (gr > MTOT-1) gr = MTOT-1;
        srcA[i] = ((s & 4) ? Al : Ah) + ((size_t)b*MTOT + gr)*CH + (s & 3)*8;
        int gc = col0 + row; if (gc > MS-1) gc = MS-1;
        srcB[i] = ((s & 4) ? Bl : Bh) + ((size_t)b*MS + gc)*CH + (s & 3)*8;
    }
    int dA = w << 10;

    f32x4 acc[4][4];
#pragma unroll
    for (int mi = 0; mi < 4; ++mi)
#pragma unroll
        for (int ni = 0; ni < 4; ++ni) acc[mi][ni] = (f32x4){0.f,0.f,0.f,0.f};

    int wr = w >> 1, wc = w & 1;
    int q = lane & 15, kg = lane >> 4;

#define STAGE(kt_) do { \
        int ko = (kt_) * BK; \
        GLD_LDS16(srcA[0] + ko, lds + 0     + dA); \
        GLD_LDS16(srcA[1] + ko, lds + 4096  + dA); \
        GLD_LDS16(srcA[2] + ko, lds + 8192  + dA); \
        GLD_LDS16(srcA[3] + ko, lds + 12288 + dA); \
        GLD_LDS16(srcB[0] + ko, lds + 16384 + dA); \
        GLD_LDS16(srcB[1] + ko, lds + 20480 + dA); \
        GLD_LDS16(srcB[2] + ko, lds + 24576 + dA); \
        GLD_LDS16(srcB[3] + ko, lds + 28672 + dA); \
    } while (0)

    for (int kt = 0; kt < NKT; ++kt) {
        STAGE(kt);
        asm volatile("s_waitcnt vmcnt(0)" ::: "memory");
        __builtin_amdgcn_sched_barrier(0);
        __builtin_amdgcn_s_barrier();
        __builtin_amdgcn_sched_barrier(0);

        bf16x8 bh[4], bl[4];
#pragma unroll
        for (int ni = 0; ni < 4; ++ni) {
            int colr = wc*64 + ni*16 + q;
            int rb = 16384 + colr*128;
            bh[ni] = *(const bf16x8*)(lds + rb + (((kg    ) ^ (colr & 7)) << 4));
            bl[ni] = *(const bf16x8*)(lds + rb + (((kg | 4) ^ (colr & 7)) << 4));
        }
#pragma unroll
        for (int mi = 0; mi < 4; ++mi) {
            int rowr = wr*64 + mi*16 + q;
            int rb = rowr*128;
            bf16x8 ah = *(const bf16x8*)(lds + rb + (((kg    ) ^ (rowr & 7)) << 4));
            bf16x8 al = *(const bf16x8*)(lds + rb + (((kg | 4) ^ (rowr & 7)) << 4));
#pragma unroll
            for (int ni = 0; ni < 4; ++ni) {
                acc[mi][ni] = __builtin_amdgcn_mfma_f32_16x16x32_bf16(ah, bh[ni], acc[mi][ni], 0, 0, 0);
                acc[mi][ni] = __builtin_amdgcn_mfma_f32_16x16x32_bf16(ah, bl[ni], acc[mi][ni], 0, 0, 0);
                acc[mi][ni] = __builtin_amdgcn_mfma_f32_16x16x32_bf16(al, bh[ni], acc[mi][ni], 0, 0, 0);
            }
        }
        __builtin_amdgcn_sched_barrier(0);
        __builtin_amdgcn_s_barrier();
        __builtin_amdgcn_sched_barrier(0);
    }
#undef STAGE

    int colb = col0 + wc*64 + q;
    int rowb = row0 + wr*64 + (kg << 2);
#pragma unroll
    for (int mi = 0; mi < 4; ++mi) {
#pragma unroll
        for (int ni = 0; ni < 4; ++ni) {
            int c = colb + ni*16;
            if (c >= MS) continue;
            float si = invs[b*MS + c];
#pragma unroll
            for (int j = 0; j < 4; ++j) {
                int r = rowb + mi*16 + j;
                if (r < MTOT)
                    S[((size_t)b*MTOT + r)*MS + c] = acc[mi][ni][j] * invq[b*MTOT + r] * si;
            }
        }
    }
}

// ---------------- K4: fused row(g20) + col(g10) softmax stats, 1024 thr ----------------
__global__ __launch_bounds__(1024) void k_stats(const float* __restrict__ S,
        float* __restrict__ m20, float* __restrict__ rd20,
        float* __restrict__ m10, float* __restrict__ rd10) {
    __shared__ float wcm[16][512];
    __shared__ float wcs[16][512];
    int sys = blockIdx.x;
    int t = threadIdx.x;
    int w = t >> 6, l = t & 63;
    const float* Sb = S + (size_t)sys*MQ*MS;
    float colm[8], cols[8];
#pragma unroll
    for (int u = 0; u < 8; ++u) { colm[u] = -1e30f; cols[u] = 0.f; }
    int nu = (l < MS - 448) ? 8 : 7;   // l<52 -> 8 cols
    for (int row = w; row < MQ; row += 16) {
        const float* rp = Sb + (size_t)row*MS;
        float v[8];
        float rm = -1e30f;
#pragma unroll
        for (int u = 0; u < 8; ++u) {
            v[u] = (u < nu) ? rp[l + 64*u] : -1e30f;
            rm = fmaxf(rm, v[u]);
        }
        for (int off = 32; off; off >>= 1) rm = fmaxf(rm, __shfl_xor(rm, off));
        float rs = 0.f;
#pragma unroll
        for (int u = 0; u < 8; ++u) if (u < nu) rs += __expf(20.f*(v[u]-rm));
        for (int off = 32; off; off >>= 1) rs += __shfl_xor(rs, off);
        if (l == 0) { m20[sys*MQ+row] = rm; rd20[sys*MQ+row] = 1.0f/rs; }
#pragma unroll
        for (int u = 0; u < 8; ++u) if (u < nu) {
            float vv = v[u];
            if (vv <= colm[u]) {
                cols[u] += __expf(10.f*(vv - colm[u]));
            } else {
                cols[u] = cols[u]*__expf(10.f*(colm[u]-vv)) + 1.0f;
                colm[u] = vv;
            }
        }
    }
#pragma unroll
    for (int u = 0; u < 8; ++u) { wcm[w][l+64*u] = colm[u]; wcs[w][l+64*u] = cols[u]; }
    __syncthreads();
    if (t < MS) {
        float m = -1e30f;
#pragma unroll
        for (int w2 = 0; w2 < 16; ++w2) m = fmaxf(m, wcm[w2][t]);
        float s = 0.f;
#pragma unroll
        for (int w2 = 0; w2 < 16; ++w2) s += wcs[w2][t]*__expf(10.f*(wcm[w2][t]-m));
        m10[sys*MS+t] = m;
        rd10[sys*MS+t] = 1.0f/s;
    }
}

// ---------------- K5: fused MFMA formB + Jacobi solve + normalize, one block/sys ----------------
__global__ __launch_bounds__(256) void k_fsolve(const float* __restrict__ S,
        const float* __restrict__ m10, const float* __restrict__ rd10,
        const float* __restrict__ m20, const float* __restrict__ rd20,
        float* __restrict__ out) {
    __shared__ __align__(16) char PQ[65536];        // PT [0,32K), QT [32K,64K); Bsh aliases
    __shared__ __align__(16) float m10s[MS], r10s[MS];
    __shared__ float m20s[MQ], r20s[MQ];
    __shared__ float xs[MQ], rh[MQ];
    __shared__ float partial[2];
    int sys = blockIdx.x;
    int t = threadIdx.x;
    int l = t & 63, w = t >> 6;
    const float* Sb = S + (size_t)sys*MQ*MS;
    char* PT = PQ;
    char* QT = PQ + 32768;

    for (int c = t; c < MS; c += 256) { m10s[c] = m10[sys*MS+c]; r10s[c] = rd10[sys*MS+c]; }
    if (t < MQ) { m20s[t] = m20[sys*MQ+t]; r20s[t] = rd20[sys*MQ+t]; }
    __syncthreads();

    int i = t >> 1, h = t & 1;
    int ccb = h*64;
    float m20i = 0.f, r20i = 0.f;
    if (i < MQ) { m20i = m20s[i]; r20i = r20s[i]; }

    f32x16 acc[4];
#pragma unroll
    for (int nt = 0; nt < 4; ++nt)
#pragma unroll
        for (int rg = 0; rg < 16; ++rg) acc[nt][rg] = 0.f;

    int rA = l & 31;
    int grA = w*32 + rA;
    int kg = l >> 5;

    for (int ck = 0; ck < 4; ++ck) {
        int c0 = ck*128;
        __syncthreads();
        if (i < MQ) {
            const float* sr = Sb + (size_t)i*MS;
#pragma unroll
            for (int j = 0; j < 16; ++j) {
                int cc = ccb + 4*j;
                int cg = c0 + cc;
                int phys = i*256 + ((((cc>>3) ^ (i&15)))<<4) + ((cc&7)*2);
                s16x4 pv, qv;
                if (cg < MS) {
                    float4 v  = *(const float4*)(sr + cg);
                    float4 m1 = *(const float4*)&m10s[cg];
                    float4 r1 = *(const float4*)&r10s[cg];
                    pv.x = (short)f2bf(__expf(10.f*(v.x - m1.x))*r1.x);
                    pv.y = (short)f2bf(__expf(10.f*(v.y - m1.y))*r1.y);
                    pv.z = (short)f2bf(__expf(10.f*(v.z - m1.z))*r1.z);
                    pv.w = (short)f2bf(__expf(10.f*(v.w - m1.w))*r1.w);
                    qv.x = (short)f2bf(__expf(20.f*(v.x - m20i))*r20i);
                    qv.y = (short)f2bf(__expf(20.f*(v.y - m20i))*r20i);
                    qv.z = (short)f2bf(__expf(20.f*(v.z - m20i))*r20i);
                    qv.w = (short)f2bf(__expf(20.f*(v.w - m20i))*r20i);
                } else {
                    pv = (s16x4){0,0,0,0}; qv = (s16x4){0,0,0,0};
                }
                *(s16x4*)(PT + phys) = pv;
                *(s16x4*)(QT + phys) = qv;
            }
        } else {
            short one = (short)0x3F80;
#pragma unroll
            for (int j = 0; j < 16; ++j) {
                int cc = ccb + 4*j;
                int cg = c0 + cc;
                int phys = i*256 + ((((cc>>3) ^ (i&15)))<<4) + ((cc&7)*2);
                s16x4 z = (s16x4){0,0,0,0};
                s16x4 qv = z;
                if (i == MQ && cg < MS) qv = (s16x4){one, one, one, one};
                *(s16x4*)(PT + phys) = z;
                *(s16x4*)(QT + phys) = qv;
            }
        }
        __syncthreads();
#pragma unroll
        for (int kk = 0; kk < 8; ++kk) {
            int sA = (kk*2 + kg) ^ (grA & 15);
            bf16x8 af = *(const bf16x8*)(PT + grA*256 + (sA<<4));
#pragma unroll
            for (int nt = 0; nt < 4; ++nt) {
                int gc = nt*32 + (l & 31);
                int sB = (kk*2 + kg) ^ (gc & 15);
                bf16x8 bfr = *(const bf16x8*)(QT + gc*256 + (sB<<4));
                acc[nt] = __builtin_amdgcn_mfma_f32_32x32x16_bf16(af, bfr, acc[nt], 0, 0, 0);
            }
        }
    }
    __syncthreads();

    float* Bsh = (float*)PQ;          // [100][101]
#pragma unroll
    for (int nt = 0; nt < 4; ++nt) {
        int col = nt*32 + (l & 31);
        if (col > MQ) continue;
#pragma unroll
        for (int rg = 0; rg < 16; ++rg) {
            int row = w*32 + (rg & 3) + 8*(rg >> 2) + 4*(l >> 5);
            if (row < MQ) Bsh[row*101 + col] = acc[nt][rg];
        }
    }
    __syncthreads();
    if (t < MQ) { rh[t] = 1.0f + 0.5f*Bsh[t*101 + 100]; xs[t] = rh[t]; }
    __syncthreads();
    for (int it = 0; it < 16; ++it) {
        float s = 0.f;
        if (t < MQ) {
            for (int j = 0; j < MQ; ++j) s += Bsh[t*101 + j]*xs[j];
        }
        __syncthreads();
        if (t < MQ) xs[t] = rh[t] + 0.25f*s;
        __syncthreads();
    }
    float kv = (t < MQ) ? (xs[t] - 1.0f) : 0.f;
    if (t < 128) {
        float s = kv;
        for (int off = 32; off; off >>= 1) s += __shfl_xor(s, off);
        if ((t & 63) == 0) partial[t >> 6] = s;
    }
    __syncthreads();
    float tot = partial[0] + partial[1];
    if (t < MQ) out[sys*MQ + t] = kv / tot;
}

extern "C" void kernel_launch(void* const* d_in, const int* in_sizes, int n_in,
                              void* d_out, int out_size, void* d_ws, size_t ws_size,
                              hipStream_t stream) {
    const float* sup = (const float*)d_in[0];
    const float* qry = (const float*)d_in[1];
    float* out = (float*)d_out;
    float* ws  = (float*)d_ws;

    float* supmean = ws;                        // 1,280,000 f (layout keeper)
    float* invs    = supmean + 1280000;         // 2,000
    float* invq    = invs + 2000;               // 30,000
    float* Smat    = invq + 30000;              // 15,000,000
    float* m20     = Smat + 15000000;           // 30,000
    float* rd20    = m20 + 30000;               // 30,000
    float* m10     = rd20 + 30000;              // 150,000
    float* rd10    = m10 + 150000;              // 150,000
    float* Bm      = rd10 + 150000;             // 3,000,000 (norm partials)
    float* rh      = Bm + 3000000;              // 30,000 (unused)
    ushort* Ahh    = (ushort*)(rh + 30000);     // 19,200,000 u16
    ushort* All    = Ahh + 19200000;            // 19,200,000
    ushort* Bhh    = All + 19200000;            // 1,280,000
    ushort* Bll    = Bhh + 1280000;             // 1,280,000
    float* npq     = Bm;                        // 10 x 30000
    float* nps     = Bm + 300000;               // 10 x 2000

    k_prep_all<<<dim3(10, 2, BATCH*NQ + BATCH*NWAY), 256, 0, stream>>>(
        qry, sup, Ahh, All, Bhh, Bll, npq, nps);
    k_finishinv<<<(NSYS*HW + BATCH*NWAY*HW + 255)/256, 256, 0, stream>>>(npq, nps, invq, invs);
    k_gemm<<<NWG, 256, 0, stream>>>(Ahh, All, Bhh, Bll, invq, invs, Smat);
    k_stats<<<NSYS, 1024, 0, stream>>>(Smat, m20, rd20, m10, rd10);
    k_fsolve<<<NSYS, 256, 0, stream>>>(Smat, m10, rd10, m20, rd20, out);
}

// Round 11
// 155.143 us; speedup vs baseline: 2.2768x; 1.2698x over previous
//
#include <hip/hip_runtime.h>
#include <math.h>

#define BATCH 4
#define NSUP 25
#define NQ   75
#define CH   640
#define HW   100
#define NWAY 5
#define KSHOT 5
#define NSYS (BATCH*NQ)   // 300
#define MS   (NWAY*HW)    // 500
#define MQ   HW           // 100
#define MTOT (NQ*HW)      // 7500 rows per batch

typedef __attribute__((ext_vector_type(8))) _Float16 f16x8;
typedef __attribute__((ext_vector_type(8))) short bf16x8;
typedef __attribute__((ext_vector_type(4))) float f32x4;
typedef __attribute__((ext_vector_type(16))) float f32x16;
typedef __attribute__((ext_vector_type(4))) short s16x4;

__device__ __forceinline__ ushort f2bf(float f) {
    unsigned u = __float_as_uint(f);
    u += 0x7fff + ((u >> 16) & 1);          // RNE
    return (ushort)(u >> 16);
}
__device__ __forceinline__ ushort f2h(float f) {
    _Float16 h = (_Float16)f;               // v_cvt_f16_f32, RNE
    return __builtin_bit_cast(unsigned short, h);
}

#define GLD_LDS16(gp, lp) __builtin_amdgcn_global_load_lds( \
    (const __attribute__((address_space(1))) unsigned*)(const void*)(gp), \
    (__attribute__((address_space(3))) unsigned*)(void*)(lp), 16, 0, 0)

// ---------------- K1: transpose + raw fp16 quantize + norm partials ----------------
// z < 300: query plane; z >= 300: support class (fused 5-shot mean)
__global__ __launch_bounds__(256) void k_prep_all(
        const float* __restrict__ qry, const float* __restrict__ sup,
        ushort* __restrict__ qh, ushort* __restrict__ sh,
        float* __restrict__ npq, float* __restrict__ nps) {
    __shared__ float tile[64][65];
    int z  = blockIdx.z;
    int c0 = blockIdx.x * 64;
    int m0 = blockIdx.y * 64;
    int t  = threadIdx.x;
    bool isq = (z < BATCH*NQ);
    int p = isq ? z : (z - BATCH*NQ);
    ushort* hi; float* normpart; int planesHW;
    if (isq) { hi = qh; normpart = npq; planesHW = NSYS*HW; }
    else     { hi = sh; normpart = nps; planesHW = BATCH*NWAY*HW; }

    if (isq) {
        const float* ib = qry + (size_t)p*CH*HW;
#pragma unroll
        for (int i = 0; i < 16; ++i) {
            int l = i*256 + t;
            int cl = l >> 6, ml = l & 63;
            int m = m0 + ml;
            tile[cl][ml] = (m < HW) ? ib[(size_t)(c0+cl)*HW + m] : 0.f;
        }
    } else {
        int b = p / NWAY, n = p % NWAY;
        const float* ib = sup + ((size_t)(b*NSUP + n*KSHOT))*CH*HW;
#pragma unroll
        for (int i = 0; i < 16; ++i) {
            int l = i*256 + t;
            int cl = l >> 6, ml = l & 63;
            int m = m0 + ml;
            float a = 0.f;
            if (m < HW) {
#pragma unroll
                for (int k = 0; k < KSHOT; ++k)
                    a += ib[((size_t)k*CH + c0 + cl)*HW + m];
            }
            tile[cl][ml] = a * 0.2f;
        }
    }
    __syncthreads();
    if (t < 64 && (m0 + t) < HW) {
        float s = 0.f;
#pragma unroll
        for (int cl = 0; cl < 64; ++cl) { float v = tile[cl][t]; s += v*v; }
        normpart[(size_t)blockIdx.x*planesHW + p*HW + m0 + t] = s;
    }
#pragma unroll
    for (int i = 0; i < 16; ++i) {
        int l = i*256 + t;
        int ml = l >> 6, cl = l & 63;
        int m = m0 + ml;
        if (m < HW) {
            size_t r = (size_t)p*HW + m;
            hi[r*CH + c0 + cl] = f2h(tile[cl][ml]);
        }
    }
}

// ---------------- K2: finish inverse norms (query + support merged) ----------------
__global__ void k_finishinv(const float* __restrict__ pq, const float* __restrict__ ps,
                            float* __restrict__ invq, float* __restrict__ invs) {
    int idx = blockIdx.x * 256 + threadIdx.x;
    if (idx < NSYS*HW) {
        float s = 0.f;
#pragma unroll
        for (int u = 0; u < 10; ++u) s += pq[(size_t)u*(NSYS*HW) + idx];
        invq[idx] = 1.0f / (1e-16f + sqrtf(s));
    } else {
        int j = idx - NSYS*HW;
        if (j < BATCH*NWAY*HW) {
            float s = 0.f;
#pragma unroll
            for (int u = 0; u < 10; ++u) s += ps[(size_t)u*(BATCH*NWAY*HW) + j];
            invs[j] = 1.0f / (1e-16f + sqrtf(s));
        }
    }
}

// ---------------- K3: fp16 single-product MFMA GEMM, 128x128 tile, dbuf+counted vmcnt ----------------
// LDS per buffer (16KB): A rows 0..127 in 8KB: row r at (r>>1)*128 + (r&1)*64;
// slot s (8 fp16) stored at sp = s ^ ((r>>1)&3).  B same at +8192.
// Reads: 2-way bank aliasing only (free).  Dbuf 2x16KB -> 5 blocks/CU + vmcnt(4) prefetch.
#define BM 128
#define BN 128
#define BK 32
#define NKT (CH/BK)           // 20
#define NCT 4
#define NRT 59
#define NWG (NCT*NRT*BATCH)   // 944, divisible by 8
__global__ __launch_bounds__(256) void k_gemm(
        const ushort* __restrict__ Ah, const ushort* __restrict__ Bh,
        const float* __restrict__ invq, const float* __restrict__ invs,
        float* __restrict__ S) {
    __shared__ __align__(1024) char lds[32768];
    int hwid = blockIdx.x;
    int l = (hwid & 7) * (NWG/8) + (hwid >> 3);   // chunked XCD swizzle
    int ct = l & 3;
    int rest = l >> 2;
    int rt = rest % NRT;
    int b  = rest / NRT;
    int t  = threadIdx.x;
    int lane = t & 63, w = t >> 6;
    int row0 = rt * BM, col0 = ct * BN;

    // staging sources: region chunk i at lds byte i*4096 + t*16 (A), 8192+ (B)
    const ushort* srcA[2];
    const ushort* srcB[2];
#pragma unroll
    for (int i = 0; i < 2; ++i) {
        int X = i*4096 + t*16;          // byte within 8KB region
        int pair = X >> 7;
        int par  = (X >> 6) & 1;
        int sp   = (X >> 4) & 3;
        int s    = sp ^ (pair & 3);
        int row  = pair*2 + par;
        int gr = row0 + row; if (gr > MTOT-1) gr = MTOT-1;
        srcA[i] = Ah + ((size_t)b*MTOT + gr)*CH + s*8;
        int gc = col0 + row; if (gc > MS-1) gc = MS-1;
        srcB[i] = Bh + ((size_t)b*MS + gc)*CH + s*8;
    }
    int dA = w << 10;

    f32x4 acc[4][4];
#pragma unroll
    for (int mi = 0; mi < 4; ++mi)
#pragma unroll
        for (int ni = 0; ni < 4; ++ni) acc[mi][ni] = (f32x4){0.f,0.f,0.f,0.f};

    int wr = w >> 1, wc = w & 1;
    int q = lane & 15, kg = lane >> 4;

#define STAGE(bufb, kt_) do { \
        int ko = (kt_) * BK; \
        char* bb = lds + (bufb)*16384; \
        GLD_LDS16(srcA[0] + ko, bb + 0     + dA); \
        GLD_LDS16(srcA[1] + ko, bb + 4096  + dA); \
        GLD_LDS16(srcB[0] + ko, bb + 8192  + dA); \
        GLD_LDS16(srcB[1] + ko, bb + 12288 + dA); \
    } while (0)

    STAGE(0, 0);
    for (int kt = 0; kt < NKT; ++kt) {
        int cur = kt & 1;
        if (kt + 1 < NKT) {
            STAGE(cur ^ 1, kt + 1);
            asm volatile("s_waitcnt vmcnt(4)" ::: "memory");
        } else {
            asm volatile("s_waitcnt vmcnt(0)" ::: "memory");
        }
        __builtin_amdgcn_sched_barrier(0);
        __builtin_amdgcn_s_barrier();
        __builtin_amdgcn_sched_barrier(0);

        const char* base = lds + cur*16384;
        f16x8 bf[4];
#pragma unroll
        for (int ni = 0; ni < 4; ++ni) {
            int c = wc*64 + ni*16 + q;
            int off = 8192 + (c>>1)*128 + (c&1)*64 + ((kg ^ ((c>>1)&3)) << 4);
            bf[ni] = *(const f16x8*)(base + off);
        }
#pragma unroll
        for (int mi = 0; mi < 4; ++mi) {
            int r = wr*64 + mi*16 + q;
            int off = (r>>1)*128 + (r&1)*64 + ((kg ^ ((r>>1)&3)) << 4);
            f16x8 af = *(const f16x8*)(base + off);
#pragma unroll
            for (int ni = 0; ni < 4; ++ni)
                acc[mi][ni] = __builtin_amdgcn_mfma_f32_16x16x32_f16(af, bf[ni], acc[mi][ni], 0, 0, 0);
        }
        __builtin_amdgcn_sched_barrier(0);
        __builtin_amdgcn_s_barrier();
        __builtin_amdgcn_sched_barrier(0);
    }
#undef STAGE

    int colb = col0 + wc*64 + q;
    int rowb = row0 + wr*64 + (kg << 2);
#pragma unroll
    for (int mi = 0; mi < 4; ++mi) {
#pragma unroll
        for (int ni = 0; ni < 4; ++ni) {
            int c = colb + ni*16;
            if (c >= MS) continue;
            float si = invs[b*MS + c];
#pragma unroll
            for (int j = 0; j < 4; ++j) {
                int r = rowb + mi*16 + j;
                if (r < MTOT)
                    S[((size_t)b*MTOT + r)*MS + c] = acc[mi][ni][j] * invq[b*MTOT + r] * si;
            }
        }
    }
}

// ---------------- K4: fused row(g20) + col(g10) softmax stats, 1024 thr ----------------
__global__ __launch_bounds__(1024) void k_stats(const float* __restrict__ S,
        float* __restrict__ m20, float* __restrict__ rd20,
        float* __restrict__ m10, float* __restrict__ rd10) {
    __shared__ float wcm[16][512];
    __shared__ float wcs[16][512];
    int sys = blockIdx.x;
    int t = threadIdx.x;
    int w = t >> 6, l = t & 63;
    const float* Sb = S + (size_t)sys*MQ*MS;
    float colm[8], cols[8];
#pragma unroll
    for (int u = 0; u < 8; ++u) { colm[u] = -1e30f; cols[u] = 0.f; }
    int nu = (l < MS - 448) ? 8 : 7;   // l<52 -> 8 cols
    for (int row = w; row < MQ; row += 16) {
        const float* rp = Sb + (size_t)row*MS;
        float v[8];
        float rm = -1e30f;
#pragma unroll
        for (int u = 0; u < 8; ++u) {
            v[u] = (u < nu) ? rp[l + 64*u] : -1e30f;
            rm = fmaxf(rm, v[u]);
        }
        for (int off = 32; off; off >>= 1) rm = fmaxf(rm, __shfl_xor(rm, off));
        float rs = 0.f;
#pragma unroll
        for (int u = 0; u < 8; ++u) if (u < nu) rs += __expf(20.f*(v[u]-rm));
        for (int off = 32; off; off >>= 1) rs += __shfl_xor(rs, off);
        if (l == 0) { m20[sys*MQ+row] = rm; rd20[sys*MQ+row] = 1.0f/rs; }
#pragma unroll
        for (int u = 0; u < 8; ++u) if (u < nu) {
            float vv = v[u];
            if (vv <= colm[u]) {
                cols[u] += __expf(10.f*(vv - colm[u]));
            } else {
                cols[u] = cols[u]*__expf(10.f*(colm[u]-vv)) + 1.0f;
                colm[u] = vv;
            }
        }
    }
#pragma unroll
    for (int u = 0; u < 8; ++u) { wcm[w][l+64*u] = colm[u]; wcs[w][l+64*u] = cols[u]; }
    __syncthreads();
    if (t < MS) {
        float m = -1e30f;
#pragma unroll
        for (int w2 = 0; w2 < 16; ++w2) m = fmaxf(m, wcm[w2][t]);
        float s = 0.f;
#pragma unroll
        for (int w2 = 0; w2 < 16; ++w2) s += wcs[w2][t]*__expf(10.f*(wcm[w2][t]-m));
        m10[sys*MS+t] = m;
        rd10[sys*MS+t] = 1.0f/s;
    }
}

// ---------------- K5: fused MFMA formB + Jacobi solve + normalize, one block/sys ----------------
__global__ __launch_bounds__(256) void k_fsolve(const float* __restrict__ S,
        const float* __restrict__ m10, const float* __restrict__ rd10,
        const float* __restrict__ m20, const float* __restrict__ rd20,
        float* __restrict__ out) {
    __shared__ __align__(16) char PQ[65536];        // PT [0,32K), QT [32K,64K); Bsh aliases
    __shared__ __align__(16) float m10s[MS], r10s[MS];
    __shared__ float m20s[MQ], r20s[MQ];
    __shared__ float xs[MQ], rh[MQ];
    __shared__ float partial[2];
    int sys = blockIdx.x;
    int t = threadIdx.x;
    int l = t & 63, w = t >> 6;
    const float* Sb = S + (size_t)sys*MQ*MS;
    char* PT = PQ;
    char* QT = PQ + 32768;

    for (int c = t; c < MS; c += 256) { m10s[c] = m10[sys*MS+c]; r10s[c] = rd10[sys*MS+c]; }
    if (t < MQ) { m20s[t] = m20[sys*MQ+t]; r20s[t] = rd20[sys*MQ+t]; }
    __syncthreads();

    int i = t >> 1, h = t & 1;
    int ccb = h*64;
    float m20i = 0.f, r20i = 0.f;
    if (i < MQ) { m20i = m20s[i]; r20i = r20s[i]; }

    f32x16 acc[4];
#pragma unroll
    for (int nt = 0; nt < 4; ++nt)
#pragma unroll
        for (int rg = 0; rg < 16; ++rg) acc[nt][rg] = 0.f;

    int rA = l & 31;
    int grA = w*32 + rA;
    int kg = l >> 5;

    for (int ck = 0; ck < 4; ++ck) {
        int c0 = ck*128;
        __syncthreads();
        if (i < MQ) {
            const float* sr = Sb + (size_t)i*MS;
#pragma unroll
            for (int j = 0; j < 16; ++j) {
                int cc = ccb + 4*j;
                int cg = c0 + cc;
                int phys = i*256 + ((((cc>>3) ^ (i&15)))<<4) + ((cc&7)*2);
                s16x4 pv, qv;
                if (cg < MS) {
                    float4 v  = *(const float4*)(sr + cg);
                    float4 m1 = *(const float4*)&m10s[cg];
                    float4 r1 = *(const float4*)&r10s[cg];
                    pv.x = (short)f2bf(__expf(10.f*(v.x - m1.x))*r1.x);
                    pv.y = (short)f2bf(__expf(10.f*(v.y - m1.y))*r1.y);
                    pv.z = (short)f2bf(__expf(10.f*(v.z - m1.z))*r1.z);
                    pv.w = (short)f2bf(__expf(10.f*(v.w - m1.w))*r1.w);
                    qv.x = (short)f2bf(__expf(20.f*(v.x - m20i))*r20i);
                    qv.y = (short)f2bf(__expf(20.f*(v.y - m20i))*r20i);
                    qv.z = (short)f2bf(__expf(20.f*(v.z - m20i))*r20i);
                    qv.w = (short)f2bf(__expf(20.f*(v.w - m20i))*r20i);
                } else {
                    pv = (s16x4){0,0,0,0}; qv = (s16x4){0,0,0,0};
                }
                *(s16x4*)(PT + phys) = pv;
                *(s16x4*)(QT + phys) = qv;
            }
        } else {
            short one = (short)0x3F80;
#pragma unroll
            for (int j = 0; j < 16; ++j) {
                int cc = ccb + 4*j;
                int cg = c0 + cc;
                int phys = i*256 + ((((cc>>3) ^ (i&15)))<<4) + ((cc&7)*2);
                s16x4 z = (s16x4){0,0,0,0};
                s16x4 qv = z;
                if (i == MQ && cg < MS) qv = (s16x4){one, one, one, one};
                *(s16x4*)(PT + phys) = z;
                *(s16x4*)(QT + phys) = qv;
            }
        }
        __syncthreads();
#pragma unroll
        for (int kk = 0; kk < 8; ++kk) {
            int sA = (kk*2 + kg) ^ (grA & 15);
            bf16x8 af = *(const bf16x8*)(PT + grA*256 + (sA<<4));
#pragma unroll
            for (int nt = 0; nt < 4; ++nt) {
                int gc = nt*32 + (l & 31);
                int sB = (kk*2 + kg) ^ (gc & 15);
                bf16x8 bfr = *(const bf16x8*)(QT + gc*256 + (sB<<4));
                acc[nt] = __builtin_amdgcn_mfma_f32_32x32x16_bf16(af, bfr, acc[nt], 0, 0, 0);
            }
        }
    }
    __syncthreads();

    float* Bsh = (float*)PQ;          // [100][101]
#pragma unroll
    for (int nt = 0; nt < 4; ++nt) {
        int col = nt*32 + (l & 31);
        if (col > MQ) continue;
#pragma unroll
        for (int rg = 0; rg < 16; ++rg) {
            int row = w*32 + (rg & 3) + 8*(rg >> 2) + 4*(l >> 5);
            if (row < MQ) Bsh[row*101 + col] = acc[nt][rg];
        }
    }
    __syncthreads();
    if (t < MQ) { rh[t] = 1.0f + 0.5f*Bsh[t*101 + 100]; xs[t] = rh[t]; }
    __syncthreads();
    for (int it = 0; it < 16; ++it) {
        float s = 0.f;
        if (t < MQ) {
            for (int j = 0; j < MQ; ++j) s += Bsh[t*101 + j]*xs[j];
        }
        __syncthreads();
        if (t < MQ) xs[t] = rh[t] + 0.25f*s;
        __syncthreads();
    }
    float kv = (t < MQ) ? (xs[t] - 1.0f) : 0.f;
    if (t < 128) {
        float s = kv;
        for (int off = 32; off; off >>= 1) s += __shfl_xor(s, off);
        if ((t & 63) == 0) partial[t >> 6] = s;
    }
    __syncthreads();
    float tot = partial[0] + partial[1];
    if (t < MQ) out[sys*MQ + t] = kv / tot;
}

extern "C" void kernel_launch(void* const* d_in, const int* in_sizes, int n_in,
                              void* d_out, int out_size, void* d_ws, size_t ws_size,
                              hipStream_t stream) {
    const float* sup = (const float*)d_in[0];
    const float* qry = (const float*)d_in[1];
    float* out = (float*)d_out;
    float* ws  = (float*)d_ws;

    float* supmean = ws;                        // 1,280,000 f (layout keeper)
    float* invs    = supmean + 1280000;         // 2,000
    float* invq    = invs + 2000;               // 30,000
    float* Smat    = invq + 30000;              // 15,000,000
    float* m20     = Smat + 15000000;           // 30,000
    float* rd20    = m20 + 30000;               // 30,000
    float* m10     = rd20 + 30000;              // 150,000
    float* rd10    = m10 + 150000;              // 150,000
    float* Bm      = rd10 + 150000;             // 3,000,000 (norm partials)
    float* rh      = Bm + 3000000;              // 30,000 (unused)
    ushort* Ahh    = (ushort*)(rh + 30000);     // 19,200,000 u16 (fp16)
    ushort* All    = Ahh + 19200000;            // (dead)
    ushort* Bhh    = All + 19200000;            // 1,280,000 u16 (fp16)
    float* npq     = Bm;                        // 10 x 30000
    float* nps     = Bm + 300000;               // 10 x 2000

    k_prep_all<<<dim3(10, 2, BATCH*NQ + BATCH*NWAY), 256, 0, stream>>>(
        qry, sup, Ahh, Bhh, npq, nps);
    k_finishinv<<<(NSYS*HW + BATCH*NWAY*HW + 255)/256, 256, 0, stream>>>(npq, nps, invq, invs);
    k_gemm<<<NWG, 256, 0, stream>>>(Ahh, Bhh, invq, invs, Smat);
    k_stats<<<NSYS, 1024, 0, stream>>>(Smat, m20, rd20, m10, rd10);
    k_fsolve<<<NSYS, 256, 0, stream>>>(Smat, m10, rd10, m20, rd20, out);
}

// Round 12
// 144.790 us; speedup vs baseline: 2.4396x; 1.0715x over previous
//
#include <hip/hip_runtime.h>
#include <math.h>

#define BATCH 4
#define NSUP 25
#define NQ   75
#define CH   640
#define HW   100
#define NWAY 5
#define KSHOT 5
#define NSYS (BATCH*NQ)   // 300
#define MS   (NWAY*HW)    // 500
#define MQ   HW           // 100
#define MTOT (NQ*HW)      // 7500 rows per batch

typedef __attribute__((ext_vector_type(8))) _Float16 f16x8;
typedef __attribute__((ext_vector_type(8))) short bf16x8;
typedef __attribute__((ext_vector_type(4))) float f32x4;
typedef __attribute__((ext_vector_type(16))) float f32x16;
typedef __attribute__((ext_vector_type(4))) short s16x4;

__device__ __forceinline__ ushort f2bf(float f) {
    unsigned u = __float_as_uint(f);
    u += 0x7fff + ((u >> 16) & 1);          // RNE
    return (ushort)(u >> 16);
}
__device__ __forceinline__ ushort f2h(float f) {
    _Float16 h = (_Float16)f;               // v_cvt_f16_f32, RNE
    return __builtin_bit_cast(unsigned short, h);
}

#define GLD_LDS16(gp, lp) __builtin_amdgcn_global_load_lds( \
    (const __attribute__((address_space(1))) unsigned*)(const void*)(gp), \
    (__attribute__((address_space(3))) unsigned*)(void*)(lp), 16, 0, 0)

// ---------------- K1: transpose + fp16 quantize + norm partials, float4/ushort8 ----------------
// block = (c-chunk of 64, plane). plane z < 300: query; z >= 300: support (5-shot mean).
__global__ __launch_bounds__(256) void k_prep_all(
        const float* __restrict__ qry, const float* __restrict__ sup,
        ushort* __restrict__ qh, ushort* __restrict__ sh,
        float* __restrict__ npq, float* __restrict__ nps) {
    __shared__ float tile[64][101];     // [c][m], odd stride -> conflict-free transpose reads
    int c0 = blockIdx.x * 64;
    int z  = blockIdx.y;
    int t  = threadIdx.x;
    bool isq = (z < BATCH*NQ);
    int p = isq ? z : (z - BATCH*NQ);
    ushort* hi; float* normpart; int planesHW;
    if (isq) { hi = qh; normpart = npq; planesHW = NSYS*HW; }
    else     { hi = sh; normpart = nps; planesHW = BATCH*NWAY*HW; }

    if (isq) {
        const float* ib = qry + (size_t)p*CH*HW;
#pragma unroll
        for (int ii = 0; ii < 7; ++ii) {
            int idx = ii*256 + t;
            if (idx < 1600) {
                int cl = idx / 25, qd = idx % 25;
                float4 v = *(const float4*)(ib + (size_t)(c0+cl)*HW + qd*4);
                tile[cl][qd*4+0] = v.x; tile[cl][qd*4+1] = v.y;
                tile[cl][qd*4+2] = v.z; tile[cl][qd*4+3] = v.w;
            }
        }
    } else {
        int b = p / NWAY, n = p % NWAY;
        const float* ib = sup + ((size_t)(b*NSUP + n*KSHOT))*CH*HW;
#pragma unroll
        for (int ii = 0; ii < 7; ++ii) {
            int idx = ii*256 + t;
            if (idx < 1600) {
                int cl = idx / 25, qd = idx % 25;
                float4 a = {0.f,0.f,0.f,0.f};
#pragma unroll
                for (int k = 0; k < KSHOT; ++k) {
                    float4 v = *(const float4*)(ib + ((size_t)k*CH + c0+cl)*HW + qd*4);
                    a.x += v.x; a.y += v.y; a.z += v.z; a.w += v.w;
                }
                tile[cl][qd*4+0] = a.x*0.2f; tile[cl][qd*4+1] = a.y*0.2f;
                tile[cl][qd*4+2] = a.z*0.2f; tile[cl][qd*4+3] = a.w*0.2f;
            }
        }
    }
    __syncthreads();
    if (t < HW) {
        float s = 0.f;
#pragma unroll
        for (int cl = 0; cl < 64; ++cl) { float v = tile[cl][t]; s += v*v; }
        normpart[(size_t)blockIdx.x*planesHW + p*HW + t] = s;
    }
    // transposed store: 800 x ushort8 (16B); LDS reads 2-way aliased (free)
#pragma unroll
    for (int ii = 0; ii < 4; ++ii) {
        int idx = ii*256 + t;
        if (idx < 800) {
            int m = idx >> 3, cb = (idx & 7) << 3;
            bf16x8 o;
#pragma unroll
            for (int j = 0; j < 8; ++j) o[j] = (short)f2h(tile[cb+j][m]);
            *(bf16x8*)(hi + ((size_t)p*HW + m)*CH + c0 + cb) = o;
        }
    }
}

// ---------------- K2: finish inverse norms (query + support merged) ----------------
__global__ void k_finishinv(const float* __restrict__ pq, const float* __restrict__ ps,
                            float* __restrict__ invq, float* __restrict__ invs) {
    int idx = blockIdx.x * 256 + threadIdx.x;
    if (idx < NSYS*HW) {
        float s = 0.f;
#pragma unroll
        for (int u = 0; u < 10; ++u) s += pq[(size_t)u*(NSYS*HW) + idx];
        invq[idx] = 1.0f / (1e-16f + sqrtf(s));
    } else {
        int j = idx - NSYS*HW;
        if (j < BATCH*NWAY*HW) {
            float s = 0.f;
#pragma unroll
            for (int u = 0; u < 10; ++u) s += ps[(size_t)u*(BATCH*NWAY*HW) + j];
            invs[j] = 1.0f / (1e-16f + sqrtf(s));
        }
    }
}

// ---------------- K3: fp16 single-product MFMA GEMM, 128x128 tile, dbuf+counted vmcnt ----------------
#define BM 128
#define BN 128
#define BK 32
#define NKT (CH/BK)           // 20
#define NCT 4
#define NRT 59
#define NWG (NCT*NRT*BATCH)   // 944, divisible by 8
__global__ __launch_bounds__(256) void k_gemm(
        const ushort* __restrict__ Ah, const ushort* __restrict__ Bh,
        const float* __restrict__ invq, const float* __restrict__ invs,
        float* __restrict__ S) {
    __shared__ __align__(1024) char lds[32768];
    int hwid = blockIdx.x;
    int l = (hwid & 7) * (NWG/8) + (hwid >> 3);   // chunked XCD swizzle
    int ct = l & 3;
    int rest = l >> 2;
    int rt = rest % NRT;
    int b  = rest / NRT;
    int t  = threadIdx.x;
    int lane = t & 63, w = t >> 6;
    int row0 = rt * BM, col0 = ct * BN;

    const ushort* srcA[2];
    const ushort* srcB[2];
#pragma unroll
    for (int i = 0; i < 2; ++i) {
        int X = i*4096 + t*16;
        int pair = X >> 7;
        int par  = (X >> 6) & 1;
        int sp   = (X >> 4) & 3;
        int s    = sp ^ (pair & 3);
        int row  = pair*2 + par;
        int gr = row0 + row; if (gr > MTOT-1) gr = MTOT-1;
        srcA[i] = Ah + ((size_t)b*MTOT + gr)*CH + s*8;
        int gc = col0 + row; if (gc > MS-1) gc = MS-1;
        srcB[i] = Bh + ((size_t)b*MS + gc)*CH + s*8;
    }
    int dA = w << 10;

    f32x4 acc[4][4];
#pragma unroll
    for (int mi = 0; mi < 4; ++mi)
#pragma unroll
        for (int ni = 0; ni < 4; ++ni) acc[mi][ni] = (f32x4){0.f,0.f,0.f,0.f};

    int wr = w >> 1, wc = w & 1;
    int q = lane & 15, kg = lane >> 4;

#define STAGE(bufb, kt_) do { \
        int ko = (kt_) * BK; \
        char* bb = lds + (bufb)*16384; \
        GLD_LDS16(srcA[0] + ko, bb + 0     + dA); \
        GLD_LDS16(srcA[1] + ko, bb + 4096  + dA); \
        GLD_LDS16(srcB[0] + ko, bb + 8192  + dA); \
        GLD_LDS16(srcB[1] + ko, bb + 12288 + dA); \
    } while (0)

    STAGE(0, 0);
    for (int kt = 0; kt < NKT; ++kt) {
        int cur = kt & 1;
        if (kt + 1 < NKT) {
            STAGE(cur ^ 1, kt + 1);
            asm volatile("s_waitcnt vmcnt(4)" ::: "memory");
        } else {
            asm volatile("s_waitcnt vmcnt(0)" ::: "memory");
        }
        __builtin_amdgcn_sched_barrier(0);
        __builtin_amdgcn_s_barrier();
        __builtin_amdgcn_sched_barrier(0);

        const char* base = lds + cur*16384;
        f16x8 bf[4];
#pragma unroll
        for (int ni = 0; ni < 4; ++ni) {
            int c = wc*64 + ni*16 + q;
            int off = 8192 + (c>>1)*128 + (c&1)*64 + ((kg ^ ((c>>1)&3)) << 4);
            bf[ni] = *(const f16x8*)(base + off);
        }
#pragma unroll
        for (int mi = 0; mi < 4; ++mi) {
            int r = wr*64 + mi*16 + q;
            int off = (r>>1)*128 + (r&1)*64 + ((kg ^ ((r>>1)&3)) << 4);
            f16x8 af = *(const f16x8*)(base + off);
#pragma unroll
            for (int ni = 0; ni < 4; ++ni)
                acc[mi][ni] = __builtin_amdgcn_mfma_f32_16x16x32_f16(af, bf[ni], acc[mi][ni], 0, 0, 0);
        }
        __builtin_amdgcn_sched_barrier(0);
        __builtin_amdgcn_s_barrier();
        __builtin_amdgcn_sched_barrier(0);
    }
#undef STAGE

    int colb = col0 + wc*64 + q;
    int rowb = row0 + wr*64 + (kg << 2);
#pragma unroll
    for (int mi = 0; mi < 4; ++mi) {
#pragma unroll
        for (int ni = 0; ni < 4; ++ni) {
            int c = colb + ni*16;
            if (c >= MS) continue;
            float si = invs[b*MS + c];
#pragma unroll
            for (int j = 0; j < 4; ++j) {
                int r = rowb + mi*16 + j;
                if (r < MTOT)
                    S[((size_t)b*MTOT + r)*MS + c] = acc[mi][ni][j] * invq[b*MTOT + r] * si;
            }
        }
    }
}

// ---------------- K4: fused row(g20) + col(g10) softmax stats, 1024 thr ----------------
__global__ __launch_bounds__(1024) void k_stats(const float* __restrict__ S,
        float* __restrict__ m20, float* __restrict__ rd20,
        float* __restrict__ m10, float* __restrict__ rd10) {
    __shared__ float wcm[16][512];
    __shared__ float wcs[16][512];
    int sys = blockIdx.x;
    int t = threadIdx.x;
    int w = t >> 6, l = t & 63;
    const float* Sb = S + (size_t)sys*MQ*MS;
    float colm[8], cols[8];
#pragma unroll
    for (int u = 0; u < 8; ++u) { colm[u] = -1e30f; cols[u] = 0.f; }
    int nu = (l < MS - 448) ? 8 : 7;   // l<52 -> 8 cols
    for (int row = w; row < MQ; row += 16) {
        const float* rp = Sb + (size_t)row*MS;
        float v[8];
        float rm = -1e30f;
#pragma unroll
        for (int u = 0; u < 8; ++u) {
            v[u] = (u < nu) ? rp[l + 64*u] : -1e30f;
            rm = fmaxf(rm, v[u]);
        }
        for (int off = 32; off; off >>= 1) rm = fmaxf(rm, __shfl_xor(rm, off));
        float rs = 0.f;
#pragma unroll
        for (int u = 0; u < 8; ++u) if (u < nu) rs += __expf(20.f*(v[u]-rm));
        for (int off = 32; off; off >>= 1) rs += __shfl_xor(rs, off);
        if (l == 0) { m20[sys*MQ+row] = rm; rd20[sys*MQ+row] = 1.0f/rs; }
#pragma unroll
        for (int u = 0; u < 8; ++u) if (u < nu) {
            float vv = v[u];
            if (vv <= colm[u]) {
                cols[u] += __expf(10.f*(vv - colm[u]));
            } else {
                cols[u] = cols[u]*__expf(10.f*(colm[u]-vv)) + 1.0f;
                colm[u] = vv;
            }
        }
    }
#pragma unroll
    for (int u = 0; u < 8; ++u) { wcm[w][l+64*u] = colm[u]; wcs[w][l+64*u] = cols[u]; }
    __syncthreads();
    if (t < MS) {
        float m = -1e30f;
#pragma unroll
        for (int w2 = 0; w2 < 16; ++w2) m = fmaxf(m, wcm[w2][t]);
        float s = 0.f;
#pragma unroll
        for (int w2 = 0; w2 < 16; ++w2) s += wcs[w2][t]*__expf(10.f*(wcm[w2][t]-m));
        m10[sys*MS+t] = m;
        rd10[sys*MS+t] = 1.0f/s;
    }
}

// ---------------- K5: fused MFMA formB + Jacobi solve + normalize, one block/sys ----------------
__global__ __launch_bounds__(256) void k_fsolve(const float* __restrict__ S,
        const float* __restrict__ m10, const float* __restrict__ rd10,
        const float* __restrict__ m20, const float* __restrict__ rd20,
        float* __restrict__ out) {
    __shared__ __align__(16) char PQ[65536];        // PT [0,32K), QT [32K,64K); Bsh aliases
    __shared__ __align__(16) float m10s[MS], r10s[MS];
    __shared__ float m20s[MQ], r20s[MQ];
    __shared__ float xs[MQ], rh[MQ];
    __shared__ float partial[2];
    int sys = blockIdx.x;
    int t = threadIdx.x;
    int l = t & 63, w = t >> 6;
    const float* Sb = S + (size_t)sys*MQ*MS;
    char* PT = PQ;
    char* QT = PQ + 32768;

    for (int c = t; c < MS; c += 256) { m10s[c] = m10[sys*MS+c]; r10s[c] = rd10[sys*MS+c]; }
    if (t < MQ) { m20s[t] = m20[sys*MQ+t]; r20s[t] = rd20[sys*MQ+t]; }
    __syncthreads();

    int i = t >> 1, h = t & 1;
    int ccb = h*64;
    float m20i = 0.f, r20i = 0.f;
    if (i < MQ) { m20i = m20s[i]; r20i = r20s[i]; }

    f32x16 acc[4];
#pragma unroll
    for (int nt = 0; nt < 4; ++nt)
#pragma unroll
        for (int rg = 0; rg < 16; ++rg) acc[nt][rg] = 0.f;

    int rA = l & 31;
    int grA = w*32 + rA;
    int kg = l >> 5;

    for (int ck = 0; ck < 4; ++ck) {
        int c0 = ck*128;
        __syncthreads();
        if (i < MQ) {
            const float* sr = Sb + (size_t)i*MS;
#pragma unroll
            for (int j = 0; j < 16; ++j) {
                int cc = ccb + 4*j;
                int cg = c0 + cc;
                int phys = i*256 + ((((cc>>3) ^ (i&15)))<<4) + ((cc&7)*2);
                s16x4 pv, qv;
                if (cg < MS) {
                    float4 v  = *(const float4*)(sr + cg);
                    float4 m1 = *(const float4*)&m10s[cg];
                    float4 r1 = *(const float4*)&r10s[cg];
                    pv.x = (short)f2bf(__expf(10.f*(v.x - m1.x))*r1.x);
                    pv.y = (short)f2bf(__expf(10.f*(v.y - m1.y))*r1.y);
                    pv.z = (short)f2bf(__expf(10.f*(v.z - m1.z))*r1.z);
                    pv.w = (short)f2bf(__expf(10.f*(v.w - m1.w))*r1.w);
                    qv.x = (short)f2bf(__expf(20.f*(v.x - m20i))*r20i);
                    qv.y = (short)f2bf(__expf(20.f*(v.y - m20i))*r20i);
                    qv.z = (short)f2bf(__expf(20.f*(v.z - m20i))*r20i);
                    qv.w = (short)f2bf(__expf(20.f*(v.w - m20i))*r20i);
                } else {
                    pv = (s16x4){0,0,0,0}; qv = (s16x4){0,0,0,0};
                }
                *(s16x4*)(PT + phys) = pv;
                *(s16x4*)(QT + phys) = qv;
            }
        } else {
            short one = (short)0x3F80;
#pragma unroll
            for (int j = 0; j < 16; ++j) {
                int cc = ccb + 4*j;
                int cg = c0 + cc;
                int phys = i*256 + ((((cc>>3) ^ (i&15)))<<4) + ((cc&7)*2);
                s16x4 z = (s16x4){0,0,0,0};
                s16x4 qv = z;
                if (i == MQ && cg < MS) qv = (s16x4){one, one, one, one};
                *(s16x4*)(PT + phys) = z;
                *(s16x4*)(QT + phys) = qv;
            }
        }
        __syncthreads();
#pragma unroll
        for (int kk = 0; kk < 8; ++kk) {
            int sA = (kk*2 + kg) ^ (grA & 15);
            bf16x8 af = *(const bf16x8*)(PT + grA*256 + (sA<<4));
#pragma unroll
            for (int nt = 0; nt < 4; ++nt) {
                int gc = nt*32 + (l & 31);
                int sB = (kk*2 + kg) ^ (gc & 15);
                bf16x8 bfr = *(const bf16x8*)(QT + gc*256 + (sB<<4));
                acc[nt] = __builtin_amdgcn_mfma_f32_32x32x16_bf16(af, bfr, acc[nt], 0, 0, 0);
            }
        }
    }
    __syncthreads();

    float* Bsh = (float*)PQ;          // [100][101]
#pragma unroll
    for (int nt = 0; nt < 4; ++nt) {
        int col = nt*32 + (l & 31);
        if (col > MQ) continue;
#pragma unroll
        for (int rg = 0; rg < 16; ++rg) {
            int row = w*32 + (rg & 3) + 8*(rg >> 2) + 4*(l >> 5);
            if (row < MQ) Bsh[row*101 + col] = acc[nt][rg];
        }
    }
    __syncthreads();
    if (t < MQ) { rh[t] = 1.0f + 0.5f*Bsh[t*101 + 100]; xs[t] = rh[t]; }
    __syncthreads();
    for (int it = 0; it < 16; ++it) {
        float s = 0.f;
        if (t < MQ) {
            for (int j = 0; j < MQ; ++j) s += Bsh[t*101 + j]*xs[j];
        }
        __syncthreads();
        if (t < MQ) xs[t] = rh[t] + 0.25f*s;
        __syncthreads();
    }
    float kv = (t < MQ) ? (xs[t] - 1.0f) : 0.f;
    if (t < 128) {
        float s = kv;
        for (int off = 32; off; off >>= 1) s += __shfl_xor(s, off);
        if ((t & 63) == 0) partial[t >> 6] = s;
    }
    __syncthreads();
    float tot = partial[0] + partial[1];
    if (t < MQ) out[sys*MQ + t] = kv / tot;
}

extern "C" void kernel_launch(void* const* d_in, const int* in_sizes, int n_in,
                              void* d_out, int out_size, void* d_ws, size_t ws_size,
                              hipStream_t stream) {
    const float* sup = (const float*)d_in[0];
    const float* qry = (const float*)d_in[1];
    float* out = (float*)d_out;
    float* ws  = (float*)d_ws;

    float* supmean = ws;                        // 1,280,000 f (layout keeper)
    float* invs    = supmean + 1280000;         // 2,000
    float* invq    = invs + 2000;               // 30,000
    float* Smat    = invq + 30000;              // 15,000,000
    float* m20     = Smat + 15000000;           // 30,000
    float* rd20    = m20 + 30000;               // 30,000
    float* m10     = rd20 + 30000;              // 150,000
    float* rd10    = m10 + 150000;              // 150,000
    float* Bm      = rd10 + 150000;             // 3,000,000 (norm partials)
    float* rh      = Bm + 3000000;              // 30,000 (unused)
    ushort* Ahh    = (ushort*)(rh + 30000);     // 19,200,000 u16 (fp16)
    ushort* All    = Ahh + 19200000;            // (dead)
    ushort* Bhh    = All + 19200000;            // 1,280,000 u16 (fp16)
    float* npq     = Bm;                        // 10 x 30000
    float* nps     = Bm + 300000;               // 10 x 2000

    k_prep_all<<<dim3(10, BATCH*NQ + BATCH*NWAY), 256, 0, stream>>>(
        qry, sup, Ahh, Bhh, npq, nps);
    k_finishinv<<<(NSYS*HW + BATCH*NWAY*HW + 255)/256, 256, 0, stream>>>(npq, nps, invq, invs);
    k_gemm<<<NWG, 256, 0, stream>>>(Ahh, Bhh, invq, invs, Smat);
    k_stats<<<NSYS, 1024, 0, stream>>>(Smat, m20, rd20, m10, rd10);
    k_fsolve<<<NSYS, 256, 0, stream>>>(Smat, m10, rd10, m20, rd20, out);
}